// Round 2
// baseline (293.654 us; speedup 1.0000x reference)
//
#include <hip/hip_runtime.h>
#include <hip/hip_cooperative_groups.h>
#include <cmath>

namespace cg = cooperative_groups;

// EmbedMaskPostProcessor: top-k select + box decode + embedding-distance masks.
// Output [2,200,384,384] f32 = 236 MB, <1% nonzero -> write-BW bound.
// Structure: k_select (cooperative, all radix passes fused; keys cached in d_out
// scratch) -> k_zero_out (nt-store memset 236 MB) -> k_box (in-box compute only).

namespace {
constexpr int NIMG = 2;
constexpr int NC   = 80;
constexpr int NHW  = 96 * 96;        // 9216
constexpr int NCHW = NC * NHW;       // 737280
constexpr int NDIM = 32;
constexpr int PH = 192, PW = 192;    // pixel_embed spatial
constexpr int OH = 384, OW = 384;    // output mask spatial
constexpr int KTOP = 200;
constexpr float PRE_THRESH = 0.05f;
constexpr unsigned KEY_ZERO = 0x80000000u;  // key of +0.0f; key > this <=> value > 0
constexpr float IMG_MAX = 767.0f;

// ws layout (4-byte words)
constexpr int WS_HIST1 = 0;                          // [NIMG][2048]
constexpr int WS_HIST2 = WS_HIST1 + NIMG * 2048;     // [NIMG][2048]
constexpr int WS_HIST3 = WS_HIST2 + NIMG * 2048;     // [NIMG][1024]
constexpr int WS_CNTA  = WS_HIST3 + NIMG * 1024;     // [NIMG]
constexpr int WS_CNTB  = WS_CNTA + NIMG;             // [NIMG]
constexpr int WS_BUFA  = WS_CNTB + NIMG;             // [NIMG][256][2] {key, refidx}
constexpr int WS_ZERO_END = WS_BUFA;                 // zero hists + counters each call
constexpr int WS_BUFB  = WS_BUFA + NIMG * 256 * 2;   // [NIMG][1024] refidx (ties)
constexpr int WS_CSIG  = WS_BUFB + NIMG * 1024;      // [NIMG][NHW] sigmoid(centerness)
constexpr int WS_PARAMS = WS_CSIG + NIMG * NHW;      // [NIMG][KTOP][40]
constexpr int PARAM_WORDS = 40;  // [0]=valid [1..4]=ix0,ix1,iy0,iy1 [5]=margin [8..39]=e

typedef float f4 __attribute__((ext_vector_type(4)));
}

// Find b* = max bucket with suffix-count >= krem_in; krem_out = krem_in - count(buckets > b*).
// All 256 threads of the block must call.
__device__ void scan_select(const unsigned* __restrict__ gh, int nb, int krem_in,
                            unsigned* sh_cnt, unsigned* sh_sum, int* sh_bk,
                            int& b_out, int& krem_out) {
  const int t = threadIdx.x;
  __syncthreads();  // protect shared reuse
  if (t == 0) { sh_bk[0] = -1; sh_bk[1] = krem_in; }
  const int per = nb >> 8;
  unsigned local = 0;
  for (int j = 0; j < per; ++j) { unsigned v = gh[t * per + j]; sh_cnt[t * per + j] = v; local += v; }
  sh_sum[t] = local;
  __syncthreads();
  unsigned S = 0;  // suffix over higher thread-chunks (broadcast reads)
  for (int j = t + 1; j < 256; ++j) S += sh_sum[j];
  int cand_b = -1;
  unsigned cand_above = 0;
  unsigned run = S;
  for (int j = per - 1; j >= 0; --j) {
    const unsigned cv = sh_cnt[t * per + j];
    if (cand_b < 0 && run + cv >= (unsigned)krem_in) { cand_b = t * per + j; cand_above = run; }
    run += cv;
  }
  if (cand_b >= 0) atomicMax(&sh_bk[0], cand_b);
  __syncthreads();
  if (cand_b >= 0 && cand_b == sh_bk[0]) sh_bk[1] = krem_in - (int)cand_above;
  __syncthreads();
  b_out = (sh_bk[0] < 0) ? 0 : sh_bk[0];
  krem_out = sh_bk[1];
}

__global__ __launch_bounds__(256) void k_select(
    const float* __restrict__ box_cls, const float* __restrict__ ctrness,
    const float* __restrict__ locations, const float* __restrict__ box_reg,
    const float* __restrict__ pemb, const float* __restrict__ pmar,
    unsigned* __restrict__ ws, unsigned* __restrict__ keys) {
  cg::grid_group grid = cg::this_grid();
  __shared__ unsigned sh_a[2048];
  __shared__ unsigned sh_sum[256];
  __shared__ int sh_bk[2];
  const int t = threadIdx.x;
  const int b = blockIdx.x;
  const int n = b >> 7;          // 128 blocks per image
  const int bi = b & 127;
  const int gstride = 128 * 256;

  // ---- phase 0: zero hists/counters; precompute sigmoid(centerness) ----
  {
    const int gid = b * 256 + t;
    for (int i = gid; i < WS_ZERO_END; i += 256 * 256) ws[i] = 0u;
    float* csig_all = reinterpret_cast<float*>(ws + WS_CSIG);
    for (int i = gid; i < NIMG * NHW; i += 256 * 256)
      csig_all[i] = 1.0f / (1.0f + expf(-ctrness[i]));
  }
  grid.sync();

  const float* cls = box_cls + n * NCHW;
  const float* csig = reinterpret_cast<const float*>(ws + WS_CSIG) + n * NHW;
  unsigned* mykeys = keys + n * NCHW;

  // ---- phase 1: compute keys once (cache in d_out scratch) + 11-bit hist ----
  for (int i = t; i < 2048; i += 256) sh_a[i] = 0;
  __syncthreads();
  for (int i = bi * 256 + t; i < NCHW; i += gstride) {
    const float x = cls[i];
    const float s = 1.0f / (1.0f + expf(-x));
    float v = -1.0f;
    if (s > PRE_THRESH) v = s * csig[i % NHW];
    const unsigned u = __float_as_uint(v);
    const unsigned k = (u & 0x80000000u) ? ~u : (u | 0x80000000u);
    mykeys[i] = k;
    atomicAdd(&sh_a[k >> 21], 1u);
  }
  __syncthreads();
  unsigned* h1 = ws + WS_HIST1 + n * 2048;
  for (int i = t; i < 2048; i += 256) { unsigned v = sh_a[i]; if (v) atomicAdd(&h1[i], v); }
  grid.sync();

  // ---- phase 2: select b1; 11-bit hist of middle bits ----
  int b1, k1;
  scan_select(h1, 2048, KTOP, sh_a, sh_sum, sh_bk, b1, k1);
  __syncthreads();
  for (int i = t; i < 2048; i += 256) sh_a[i] = 0;
  __syncthreads();
  const unsigned p1 = (unsigned)b1;
  for (int i = bi * 256 + t; i < NCHW; i += gstride) {
    const unsigned k = mykeys[i];
    if ((k >> 21) == p1) atomicAdd(&sh_a[(k >> 10) & 2047u], 1u);
  }
  __syncthreads();
  unsigned* h2 = ws + WS_HIST2 + n * 2048;
  for (int i = t; i < 2048; i += 256) { unsigned v = sh_a[i]; if (v) atomicAdd(&h2[i], v); }
  grid.sync();

  // ---- phase 3: select b2; 10-bit hist of low bits ----
  int b2, k2;
  scan_select(h2, 2048, k1, sh_a, sh_sum, sh_bk, b2, k2);
  __syncthreads();
  for (int i = t; i < 1024; i += 256) sh_a[i] = 0;
  __syncthreads();
  const unsigned p22 = (p1 << 11) | (unsigned)b2;
  for (int i = bi * 256 + t; i < NCHW; i += gstride) {
    const unsigned k = mykeys[i];
    if ((k >> 10) == p22) atomicAdd(&sh_a[k & 1023u], 1u);
  }
  __syncthreads();
  unsigned* h3 = ws + WS_HIST3 + n * 1024;
  for (int i = t; i < 1024; i += 256) { unsigned v = sh_a[i]; if (v) atomicAdd(&h3[i], v); }
  grid.sync();

  // ---- phase 4: exact 32-bit threshold; gather winners + ties ----
  int b3, k3;
  scan_select(h3, 1024, k2, sh_a, sh_sum, sh_bk, b3, k3);
  const unsigned thresh = (p22 << 10) | (unsigned)b3;
  for (int i = bi * 256 + t; i < NCHW; i += gstride) {
    const unsigned k = mykeys[i];
    if (k < thresh) continue;
    const int c = i / NHW;
    const int hw = i - c * NHW;
    const unsigned ref = (unsigned)(hw * NC + c);  // reference flat index (tie-break order)
    if (k > thresh) {
      const unsigned pos = atomicAdd(ws + WS_CNTA + n, 1u);
      if (pos < 256u) {
        ws[WS_BUFA + (n * 256 + (int)pos) * 2] = k;
        ws[WS_BUFA + (n * 256 + (int)pos) * 2 + 1] = ref;
      }
    } else {
      const unsigned pos = atomicAdd(ws + WS_CNTB + n, 1u);
      if (pos < 1024u) ws[WS_BUFB + n * 1024 + (int)pos] = ref;
    }
  }
  grid.sync();

  // ---- phase 5: exact ranking + param build (one block per image) ----
  if (bi != 0) return;
  unsigned* aKey = sh_a;               // 256
  unsigned* aRef = sh_a + 256;         // 256
  int* slotRef = (int*)(sh_a + 512);   // 256
  unsigned* slotKey = sh_a + 768;      // 256
  unsigned* sB = sh_a + 1024;          // 1024
  __syncthreads();
  const int cntA = min((int)ws[WS_CNTA + n], 256);
  const int cntB = min((int)ws[WS_CNTB + n], 1024);
  if (t < cntA) {
    aKey[t] = ws[WS_BUFA + (n * 256 + t) * 2];
    aRef[t] = ws[WS_BUFA + (n * 256 + t) * 2 + 1];
  }
  slotRef[t] = -1;
  slotKey[t] = 0u;
  for (int i = t; i < cntB; i += 256) sB[i] = ws[WS_BUFB + n * 1024 + i];
  __syncthreads();
  if (t < cntA) {  // exact rank: value desc, index asc (matches lax.top_k)
    const unsigned mk = aKey[t], mr = aRef[t];
    int rank = 0;
    for (int j = 0; j < cntA; ++j) {
      const unsigned kj = aKey[j], rj = aRef[j];
      rank += (kj > mk || (kj == mk && rj < mr)) ? 1 : 0;
    }
    slotRef[rank] = (int)mr;
    slotKey[rank] = mk;
  }
  const bool tieValid = thresh > KEY_ZERO;
  int take = min(min(k3, cntB), KTOP - cntA);
  if (take < 0) take = 0;
  if (tieValid) {
    for (int i = t; i < cntB; i += 256) {
      const unsigned mr = sB[i];
      int r = 0;
      for (int j = 0; j < cntB; ++j) r += (sB[j] < mr) ? 1 : 0;
      if (r < take) { slotRef[cntA + r] = (int)mr; slotKey[cntA + r] = thresh; }
    }
  }
  __syncthreads();
  if (t < KTOP) {
    const int ref = slotRef[t];
    const unsigned key = slotKey[t];
    unsigned* pp = ws + WS_PARAMS + (n * KTOP + t) * PARAM_WORDS;
    int valid = 0;
    if (ref >= 0 && key > KEY_ZERO) {
      const int hw = ref / NC;
      const float lx = locations[2 * hw], ly = locations[2 * hw + 1];
      const float rl = box_reg[(n * 4 + 0) * NHW + hw];
      const float rt = box_reg[(n * 4 + 1) * NHW + hw];
      const float rr = box_reg[(n * 4 + 2) * NHW + hw];
      const float rb = box_reg[(n * 4 + 3) * NHW + hw];
      const float x1 = fminf(fmaxf(lx - rl, 0.f), IMG_MAX);
      const float y1 = fminf(fmaxf(ly - rt, 0.f), IMG_MAX);
      const float x2 = fminf(fmaxf(lx + rr, 0.f), IMG_MAX);
      const float y2 = fminf(fmaxf(ly + rb, 0.f), IMG_MAX);
      // mask coords = box/4; inclusive integer bounds (xs >= x1m && xs <= x2m)
      const int ix0 = max(0, (int)ceilf(x1 * 0.25f));
      const int ix1 = min(OW - 1, (int)floorf(x2 * 0.25f));
      const int iy0 = max(0, (int)ceilf(y1 * 0.25f));
      const int iy1 = min(OH - 1, (int)floorf(y2 * 0.25f));
      if (ix0 <= ix1 && iy0 <= iy1) {
        valid = 1;
        pp[1] = (unsigned)ix0; pp[2] = (unsigned)ix1;
        pp[3] = (unsigned)iy0; pp[4] = (unsigned)iy1;
        reinterpret_cast<float*>(pp)[5] = pmar[n * NHW + hw];
        float* ep = reinterpret_cast<float*>(pp) + 8;
        #pragma unroll
        for (int d = 0; d < NDIM; ++d) ep[d] = pemb[(n * NDIM + d) * NHW + hw];
      }
    }
    pp[0] = (unsigned)valid;
  }
}

// Full-output streaming zero with nontemporal 16B stores.
__global__ __launch_bounds__(256) void k_zero_out(f4* __restrict__ out, int n4) {
  const f4 z = {0.f, 0.f, 0.f, 0.f};
  for (int i = blockIdx.x * 256 + threadIdx.x; i < n4; i += gridDim.x * 256)
    __builtin_nontemporal_store(z, out + i);
}

// In-box compute only: one block per (n,k). 64 columns x 4 row-strips; each
// thread walks a column with register-staged x-interpolated source rows
// (2x upsample => one new source row per two output rows -> 4x fewer loads).
__global__ __launch_bounds__(256) void k_box(const float* __restrict__ pix,
                                             const unsigned* __restrict__ ws,
                                             float* __restrict__ out) {
  const int nk = blockIdx.x;  // n*KTOP + k
  const unsigned* meta = ws + WS_PARAMS + nk * PARAM_WORDS;
  if (meta[0] == 0u) return;
  const int ix0 = (int)meta[1], ix1 = (int)meta[2];
  const int iy0 = (int)meta[3], iy1 = (int)meta[4];
  const float margin = __uint_as_float(meta[5]);
  float e[NDIM];
  {
    const float4* e4 = reinterpret_cast<const float4*>(meta + 8);
    #pragma unroll
    for (int q = 0; q < NDIM / 4; ++q) {
      const float4 v = e4[q];
      e[4 * q + 0] = v.x; e[4 * q + 1] = v.y; e[4 * q + 2] = v.z; e[4 * q + 3] = v.w;
    }
  }
  const int n = nk / KTOP;
  const float* peb = pix + (size_t)n * NDIM * PH * PW;
  float* ob = out + (size_t)nk * (OH * OW);

  const int tx = threadIdx.x & 63;   // column lane
  const int ts = threadIdx.x >> 6;   // row strip 0..3
  const int h = iy1 - iy0 + 1;
  const int shh = (h + 3) >> 2;
  const int ybeg = iy0 + ts * shh;
  const int yend = min(iy0 + (ts + 1) * shh, iy1 + 1);

  for (int c = ix0 + tx; c <= ix1; c += 64) {
    const float sx = 0.5f * (float)c - 0.25f;
    const float xf = floorf(sx);
    const float fx = sx - xf;
    const int xs0 = max((int)xf, 0);
    const int xs1 = min((int)xf + 1, PW - 1);
    float qa[NDIM], qb[NDIM];
    int ra = -9, rb = -9;
    for (int y = ybeg; y < yend; ++y) {
      const float sy = 0.5f * (float)y - 0.25f;
      const float yf = floorf(sy);
      const float fy = sy - yf;
      const int ys0 = max((int)yf, 0);
      const int ys1 = min((int)yf + 1, PH - 1);
      if (ys0 != ra) {
        if (ys0 == rb) {
          #pragma unroll
          for (int d = 0; d < NDIM; ++d) qa[d] = qb[d];
        } else {
          const float* p = peb + (size_t)ys0 * PW;
          #pragma unroll
          for (int d = 0; d < NDIM; ++d)
            qa[d] = (1.f - fx) * p[d * PH * PW + xs0] + fx * p[d * PH * PW + xs1];
        }
        ra = ys0;
      }
      if (ys1 != rb) {
        if (ys1 == ra) {
          #pragma unroll
          for (int d = 0; d < NDIM; ++d) qb[d] = qa[d];
        } else {
          const float* p = peb + (size_t)ys1 * PW;
          #pragma unroll
          for (int d = 0; d < NDIM; ++d)
            qb[d] = (1.f - fx) * p[d * PH * PW + xs0] + fx * p[d * PH * PW + xs1];
        }
        rb = ys1;
      }
      float d2 = 0.f;
      #pragma unroll
      for (int d = 0; d < NDIM; ++d) {
        const float pv = qa[d] + fy * (qb[d] - qa[d]);
        const float df = e[d] - pv;
        d2 = fmaf(df, df, d2);
      }
      ob[(size_t)y * OW + c] = expf(-d2 * margin);
    }
  }
}

extern "C" void kernel_launch(void* const* d_in, const int* in_sizes, int n_in,
                              void* d_out, int out_size, void* d_ws, size_t ws_size,
                              hipStream_t stream) {
  const float* locations = (const float*)d_in[0];
  const float* box_cls   = (const float*)d_in[1];
  const float* box_reg   = (const float*)d_in[2];
  const float* ctrness   = (const float*)d_in[3];
  const float* pemb      = (const float*)d_in[4];
  const float* pmar      = (const float*)d_in[5];
  const float* pix       = (const float*)d_in[6];
  float* out = (float*)d_out;
  unsigned* ws = (unsigned*)d_ws;
  unsigned* keys = (unsigned*)d_out;  // 5.9 MB scratch; overwritten by k_zero_out after use

  void* args[] = { (void*)&box_cls, (void*)&ctrness, (void*)&locations, (void*)&box_reg,
                   (void*)&pemb, (void*)&pmar, (void*)&ws, (void*)&keys };
  hipLaunchCooperativeKernel((void*)k_select, dim3(256), dim3(256), args, 0, stream);

  const int n4 = out_size / 4;  // 14,745,600 float4
  k_zero_out<<<dim3(2048), dim3(256), 0, stream>>>((f4*)d_out, n4);
  k_box<<<dim3(NIMG * KTOP), dim3(256), 0, stream>>>(pix, ws, out);
}

// Round 3
// 279.107 us; speedup vs baseline: 1.0521x; 1.0521x over previous
//
#include <hip/hip_runtime.h>
#include <cmath>

// EmbedMaskPostProcessor: top-k select + box decode + embedding-distance masks.
// Output [2,200,384,384] f32 = 236 MB, <1% nonzero -> write-BW bound.
// R3 structure: keygen+hist (1 sweep) -> scan -> gather band (1 sweep) ->
// exact rank in LDS -> nt-store zero (236 MB) -> in-box compute.
// R2 lesson: cooperative grid.sync was 10x slower than separate launches.

namespace {
constexpr int NIMG = 2;
constexpr int NC   = 80;
constexpr int NHW  = 96 * 96;        // 9216
constexpr int NCHW = NC * NHW;       // 737280
constexpr int NDIM = 32;
constexpr int PH = 192, PW = 192;    // pixel_embed spatial
constexpr int OH = 384, OW = 384;    // output mask spatial
constexpr int KTOP = 200;
constexpr int CAP = 4096;            // gathered band candidates per image
constexpr float PRE_THRESH = 0.05f;
constexpr unsigned KEY_ZERO = 0x80000000u;  // key of +0.0f; key > this <=> value > 0
constexpr float IMG_MAX = 767.0f;

// ws layout (4-byte words)
constexpr int WS_HIST1  = 0;                         // [NIMG][2048]
constexpr int WS_CNT    = WS_HIST1 + NIMG * 2048;    // [NIMG] gathered count
constexpr int WS_B1     = WS_CNT + NIMG;             // [NIMG]
constexpr int WS_KREM1  = WS_B1 + NIMG;              // [NIMG]
constexpr int WS_PAIRS  = 4104;                      // [NIMG][CAP][2] {key,ref} (8B aligned)
constexpr int WS_PARAMS = WS_PAIRS + NIMG * CAP * 2; // [NIMG][KTOP][40]
constexpr int PARAM_WORDS = 40;  // [0]=valid [1..4]=ix0,ix1,iy0,iy1 [5]=margin [8..39]=e
constexpr int WS_ZERO_WORDS = WS_CNT + NIMG;         // memset range (hist + counts)

typedef float f4 __attribute__((ext_vector_type(4)));
}

__device__ __forceinline__ unsigned key_of(float f) {
  unsigned u = __float_as_uint(f);
  return (u & 0x80000000u) ? ~u : (u | 0x80000000u);  // monotone: bigger float -> bigger key
}

// Find b* = max bucket (of 2048) with suffix-count >= kwant; kr_out = kwant - count(buckets > b*).
// All 256 threads must call. Shared arrays provided by caller.
__device__ void scan2048(const unsigned* __restrict__ gh, int kwant,
                         unsigned* sh_cnt, unsigned* sh_sum, int* sh_bk,
                         int& b_out, int& kr_out) {
  const int t = threadIdx.x;
  __syncthreads();
  if (t == 0) { sh_bk[0] = -1; sh_bk[1] = kwant; }
  unsigned local = 0;
  for (int j = 0; j < 8; ++j) { unsigned v = gh[t * 8 + j]; sh_cnt[t * 8 + j] = v; local += v; }
  sh_sum[t] = local;
  __syncthreads();
  unsigned S = 0;
  for (int j = t + 1; j < 256; ++j) S += sh_sum[j];
  int cand_b = -1;
  unsigned cand_above = 0;
  unsigned run = S;
  for (int j = 7; j >= 0; --j) {
    const unsigned cv = sh_cnt[t * 8 + j];
    if (cand_b < 0 && run + cv >= (unsigned)kwant) { cand_b = t * 8 + j; cand_above = run; }
    run += cv;
  }
  if (cand_b >= 0) atomicMax(&sh_bk[0], cand_b);
  __syncthreads();
  if (cand_b >= 0 && cand_b == sh_bk[0]) sh_bk[1] = kwant - (int)cand_above;
  __syncthreads();
  b_out = (sh_bk[0] < 0) ? 0 : sh_bk[0];
  kr_out = sh_bk[1];
}

// One float4 per thread over [NIMG][NCHW]; keys cached in d_out scratch.
// Blocks 0..719 -> image 0, 720..1439 -> image 1 (NCHW/1024 = 720 exactly).
__global__ __launch_bounds__(256) void k_keygen(const float* __restrict__ box_cls,
                                                const float* __restrict__ ctrness,
                                                unsigned* __restrict__ ws,
                                                uint4* __restrict__ keys) {
  __shared__ unsigned hist[2048];
  for (int i = threadIdx.x; i < 2048; i += 256) hist[i] = 0;
  __syncthreads();
  const int n = blockIdx.x >= 720;
  const int i4 = blockIdx.x * 256 + threadIdx.x;           // global float4 index
  const int i = i4 * 4;                                    // flat elem index
  const int j = i - n * NCHW;                              // offset within image
  const int c = j / NHW;
  const int hw = j - c * NHW;                              // multiple of 4
  const f4 xv = *reinterpret_cast<const f4*>(box_cls + i);
  const f4 cv = *reinterpret_cast<const f4*>(ctrness + n * NHW + hw);
  unsigned kk[4];
  #pragma unroll
  for (int q = 0; q < 4; ++q) {
    const float s = 1.0f / (1.0f + expf(-xv[q]));
    float v = -1.0f;
    if (s > PRE_THRESH) v = s * (1.0f / (1.0f + expf(-cv[q])));
    const unsigned k = key_of(v);
    kk[q] = k;
    if (k > KEY_ZERO) atomicAdd(&hist[k >> 21], 1u);       // hist positives only
  }
  keys[i4] = make_uint4(kk[0], kk[1], kk[2], kk[3]);
  __syncthreads();
  unsigned* gh = ws + WS_HIST1 + n * 2048;
  for (int t = threadIdx.x; t < 2048; t += 256) { unsigned v = hist[t]; if (v) atomicAdd(&gh[t], v); }
}

__global__ __launch_bounds__(256) void k_scan1(unsigned* __restrict__ ws) {
  __shared__ unsigned sh_cnt[2048];
  __shared__ unsigned sh_sum[256];
  __shared__ int sh_bk[2];
  const int n = blockIdx.x;
  int b1, kr;
  scan2048(ws + WS_HIST1 + n * 2048, KTOP, sh_cnt, sh_sum, sh_bk, b1, kr);
  if (threadIdx.x == 0) { ws[WS_B1 + n] = (unsigned)b1; ws[WS_KREM1 + n] = (unsigned)kr; }
}

// Compact all candidates with top-11 bucket >= b1 into ws pairs {key, ref}.
__global__ __launch_bounds__(256) void k_gather(const uint4* __restrict__ keys,
                                                unsigned* __restrict__ ws) {
  const int n = blockIdx.x >= 720;
  const unsigned b1 = ws[WS_B1 + n];
  const int i4 = blockIdx.x * 256 + threadIdx.x;
  const uint4 kv = keys[i4];
  const unsigned kk[4] = {kv.x, kv.y, kv.z, kv.w};
  #pragma unroll
  for (int q = 0; q < 4; ++q) {
    const unsigned k = kk[q];
    if ((k >> 21) < b1) continue;
    const int i = i4 * 4 + q;
    const int j = i - n * NCHW;
    const int c = j / NHW;
    const int hw = j - c * NHW;
    const unsigned ref = (unsigned)(hw * NC + c);          // reference flat order index
    const unsigned pos = atomicAdd(ws + WS_CNT + n, 1u);
    if (pos < (unsigned)CAP) {
      ws[WS_PAIRS + (n * CAP + (int)pos) * 2]     = k;
      ws[WS_PAIRS + (n * CAP + (int)pos) * 2 + 1] = ref;
    }
  }
}

// One block per image: refine band by next 8 bits, exact rank (value desc,
// index asc = lax.top_k), build per-slot params.
__global__ __launch_bounds__(256) void k_final(unsigned* __restrict__ ws,
                                               const float* __restrict__ locations,
                                               const float* __restrict__ box_reg,
                                               const float* __restrict__ pemb,
                                               const float* __restrict__ pmar) {
  const int n = blockIdx.x;
  const int t = threadIdx.x;
  __shared__ uint2 P[CAP];           // 32 KiB
  __shared__ unsigned h256[256];
  __shared__ int sh_b2;
  // pre-init all slots invalid (guards any unfilled-slot path)
  for (int s = t; s < KTOP; s += 256) ws[WS_PARAMS + (n * KTOP + s) * PARAM_WORDS] = 0u;
  const unsigned b1 = ws[WS_B1 + n];
  const int krem1 = (int)ws[WS_KREM1 + n];
  const int cnt = min((int)ws[WS_CNT + n], CAP);
  for (int i = t; i < cnt; i += 256) {
    P[i].x = ws[WS_PAIRS + (n * CAP + i) * 2];
    P[i].y = ws[WS_PAIRS + (n * CAP + i) * 2 + 1];
  }
  h256[t] = 0;
  if (t == 0) sh_b2 = 0;
  __syncthreads();
  for (int i = t; i < cnt; i += 256) {
    const unsigned k = P[i].x;
    if ((k >> 21) == b1) atomicAdd(&h256[(k >> 13) & 255u], 1u);
  }
  __syncthreads();
  // suffix scan over 256 refine buckets: b2 = max t with suffix_incl(t) >= krem1
  {
    const unsigned hv = h256[t];
    unsigned S = 0;
    for (int j = t + 1; j < 256; ++j) S += h256[j];
    if (S + hv >= (unsigned)krem1) atomicMax(&sh_b2, t);
    __syncthreads();
  }
  const unsigned prefix19 = (b1 << 8) | (unsigned)sh_b2;
  // rank members (key>>13 >= prefix19 includes all above-b1-band too) and emit
  for (int i = t; i < cnt; i += 256) {
    const unsigned ki = P[i].x, ri = P[i].y;
    if ((ki >> 13) < prefix19) continue;
    int rank = 0;
    for (int j = 0; j < cnt; ++j) {
      const unsigned kj = P[j].x, rj = P[j].y;
      rank += (kj > ki || (kj == ki && rj < ri)) ? 1 : 0;
    }
    if (rank >= KTOP) continue;
    unsigned* pp = ws + WS_PARAMS + (n * KTOP + rank) * PARAM_WORDS;
    int valid = 0;
    if (ki > KEY_ZERO) {
      const int hw = (int)ri / NC;
      const float lx = locations[2 * hw], ly = locations[2 * hw + 1];
      const float rl = box_reg[(n * 4 + 0) * NHW + hw];
      const float rt = box_reg[(n * 4 + 1) * NHW + hw];
      const float rr = box_reg[(n * 4 + 2) * NHW + hw];
      const float rb = box_reg[(n * 4 + 3) * NHW + hw];
      const float x1 = fminf(fmaxf(lx - rl, 0.f), IMG_MAX);
      const float y1 = fminf(fmaxf(ly - rt, 0.f), IMG_MAX);
      const float x2 = fminf(fmaxf(lx + rr, 0.f), IMG_MAX);
      const float y2 = fminf(fmaxf(ly + rb, 0.f), IMG_MAX);
      const int ix0 = max(0, (int)ceilf(x1 * 0.25f));
      const int ix1 = min(OW - 1, (int)floorf(x2 * 0.25f));
      const int iy0 = max(0, (int)ceilf(y1 * 0.25f));
      const int iy1 = min(OH - 1, (int)floorf(y2 * 0.25f));
      if (ix0 <= ix1 && iy0 <= iy1) {
        valid = 1;
        pp[1] = (unsigned)ix0; pp[2] = (unsigned)ix1;
        pp[3] = (unsigned)iy0; pp[4] = (unsigned)iy1;
        reinterpret_cast<float*>(pp)[5] = pmar[n * NHW + hw];
        float* ep = reinterpret_cast<float*>(pp) + 8;
        #pragma unroll
        for (int d = 0; d < NDIM; ++d) ep[d] = pemb[(n * NDIM + d) * NHW + hw];
      }
    }
    pp[0] = (unsigned)valid;
  }
}

// Full-output streaming zero with nontemporal 16B stores.
__global__ __launch_bounds__(256) void k_zero_out(f4* __restrict__ out, int n4) {
  const f4 z = {0.f, 0.f, 0.f, 0.f};
  for (int i = blockIdx.x * 256 + threadIdx.x; i < n4; i += gridDim.x * 256)
    __builtin_nontemporal_store(z, out + i);
}

// In-box compute only: one block per (n,k). 64 columns x 4 row-strips; each
// thread walks a column with register-staged x-interpolated source rows.
__global__ __launch_bounds__(256) void k_box(const float* __restrict__ pix,
                                             const unsigned* __restrict__ ws,
                                             float* __restrict__ out) {
  const int nk = blockIdx.x;  // n*KTOP + k
  const unsigned* meta = ws + WS_PARAMS + nk * PARAM_WORDS;
  if (meta[0] == 0u) return;
  const int ix0 = (int)meta[1], ix1 = (int)meta[2];
  const int iy0 = (int)meta[3], iy1 = (int)meta[4];
  const float margin = __uint_as_float(meta[5]);
  float e[NDIM];
  {
    const float4* e4 = reinterpret_cast<const float4*>(meta + 8);
    #pragma unroll
    for (int q = 0; q < NDIM / 4; ++q) {
      const float4 v = e4[q];
      e[4 * q + 0] = v.x; e[4 * q + 1] = v.y; e[4 * q + 2] = v.z; e[4 * q + 3] = v.w;
    }
  }
  const int n = nk / KTOP;
  const float* peb = pix + (size_t)n * NDIM * PH * PW;
  float* ob = out + (size_t)nk * (OH * OW);

  const int tx = threadIdx.x & 63;   // column lane
  const int ts = threadIdx.x >> 6;   // row strip 0..3
  const int h = iy1 - iy0 + 1;
  const int shh = (h + 3) >> 2;
  const int ybeg = iy0 + ts * shh;
  const int yend = min(iy0 + (ts + 1) * shh, iy1 + 1);

  for (int c = ix0 + tx; c <= ix1; c += 64) {
    const float sx = 0.5f * (float)c - 0.25f;
    const float xf = floorf(sx);
    const float fx = sx - xf;
    const int xs0 = max((int)xf, 0);
    const int xs1 = min((int)xf + 1, PW - 1);
    float qa[NDIM], qb[NDIM];
    int ra = -9, rb = -9;
    for (int y = ybeg; y < yend; ++y) {
      const float sy = 0.5f * (float)y - 0.25f;
      const float yf = floorf(sy);
      const float fy = sy - yf;
      const int ys0 = max((int)yf, 0);
      const int ys1 = min((int)yf + 1, PH - 1);
      if (ys0 != ra) {
        if (ys0 == rb) {
          #pragma unroll
          for (int d = 0; d < NDIM; ++d) qa[d] = qb[d];
        } else {
          const float* p = peb + (size_t)ys0 * PW;
          #pragma unroll
          for (int d = 0; d < NDIM; ++d)
            qa[d] = (1.f - fx) * p[d * PH * PW + xs0] + fx * p[d * PH * PW + xs1];
        }
        ra = ys0;
      }
      if (ys1 != rb) {
        if (ys1 == ra) {
          #pragma unroll
          for (int d = 0; d < NDIM; ++d) qb[d] = qa[d];
        } else {
          const float* p = peb + (size_t)ys1 * PW;
          #pragma unroll
          for (int d = 0; d < NDIM; ++d)
            qb[d] = (1.f - fx) * p[d * PH * PW + xs0] + fx * p[d * PH * PW + xs1];
        }
        rb = ys1;
      }
      float d2 = 0.f;
      #pragma unroll
      for (int d = 0; d < NDIM; ++d) {
        const float pv = qa[d] + fy * (qb[d] - qa[d]);
        const float df = e[d] - pv;
        d2 = fmaf(df, df, d2);
      }
      ob[(size_t)y * OW + c] = expf(-d2 * margin);
    }
  }
}

extern "C" void kernel_launch(void* const* d_in, const int* in_sizes, int n_in,
                              void* d_out, int out_size, void* d_ws, size_t ws_size,
                              hipStream_t stream) {
  const float* locations = (const float*)d_in[0];
  const float* box_cls   = (const float*)d_in[1];
  const float* box_reg   = (const float*)d_in[2];
  const float* ctrness   = (const float*)d_in[3];
  const float* pemb      = (const float*)d_in[4];
  const float* pmar      = (const float*)d_in[5];
  const float* pix       = (const float*)d_in[6];
  float* out = (float*)d_out;
  unsigned* ws = (unsigned*)d_ws;
  uint4* keys = (uint4*)d_out;  // 5.9 MB scratch; overwritten by k_zero_out afterwards
  // ws need: (WS_PARAMS + NIMG*KTOP*40)*4 ~= 146 KB

  hipMemsetAsync(ws, 0, (size_t)WS_ZERO_WORDS * 4, stream);
  k_keygen<<<dim3(1440), dim3(256), 0, stream>>>(box_cls, ctrness, ws, keys);
  k_scan1 <<<dim3(NIMG), dim3(256), 0, stream>>>(ws);
  k_gather<<<dim3(1440), dim3(256), 0, stream>>>(keys, ws);
  k_final <<<dim3(NIMG), dim3(256), 0, stream>>>(ws, locations, box_reg, pemb, pmar);
  const int n4 = out_size / 4;  // 14,745,600 float4
  k_zero_out<<<dim3(4096), dim3(256), 0, stream>>>((f4*)d_out, n4);
  k_box<<<dim3(NIMG * KTOP), dim3(256), 0, stream>>>(pix, ws, out);
}

// Round 4
// 150.904 us; speedup vs baseline: 1.9460x; 1.8496x over previous
//
#include <hip/hip_runtime.h>
#include <cmath>

// EmbedMaskPostProcessor: top-k select + box decode + embedding-distance masks.
// Output [2,200,384,384] f32 = 236 MB, <1% nonzero -> write-BW bound.
// R4: k_final reworked — refine radix prefix to 27 bits in LDS, then rank only
// within members (m ~ 205) instead of O(m x 4096). R3's k_final was 200us of
// serialized LDS latency from ranking against the whole gathered band.

namespace {
constexpr int NIMG = 2;
constexpr int NC   = 80;
constexpr int NHW  = 96 * 96;        // 9216
constexpr int NCHW = NC * NHW;       // 737280
constexpr int NDIM = 32;
constexpr int PH = 192, PW = 192;    // pixel_embed spatial
constexpr int OH = 384, OW = 384;    // output mask spatial
constexpr int KTOP = 200;
constexpr int CAP = 4096;            // gathered band candidates per image
constexpr int MCAP = 1024;           // member cap after 27-bit refine
constexpr float PRE_THRESH = 0.05f;
constexpr unsigned KEY_ZERO = 0x80000000u;  // key of +0.0f; key > this <=> value > 0
constexpr float IMG_MAX = 767.0f;

// ws layout (4-byte words)
constexpr int WS_HIST1  = 0;                         // [NIMG][2048]
constexpr int WS_CNT    = WS_HIST1 + NIMG * 2048;    // [NIMG] gathered count
constexpr int WS_B1     = WS_CNT + NIMG;             // [NIMG]
constexpr int WS_KREM1  = WS_B1 + NIMG;              // [NIMG]
constexpr int WS_PAIRS  = 4104;                      // [NIMG][CAP][2] {key,ref} (8B aligned)
constexpr int WS_PARAMS = WS_PAIRS + NIMG * CAP * 2; // [NIMG][KTOP][40]
constexpr int PARAM_WORDS = 40;  // [0]=valid [1..4]=ix0,ix1,iy0,iy1 [5]=margin [8..39]=e
constexpr int WS_ZERO_WORDS = WS_CNT + NIMG;         // memset range (hist + counts)

typedef float f4 __attribute__((ext_vector_type(4)));
}

__device__ __forceinline__ unsigned key_of(float f) {
  unsigned u = __float_as_uint(f);
  return (u & 0x80000000u) ? ~u : (u | 0x80000000u);  // monotone: bigger float -> bigger key
}

// Find b* = max bucket (of 2048) with suffix-count >= kwant; kr_out = kwant - count(buckets > b*).
__device__ void scan2048(const unsigned* __restrict__ gh, int kwant,
                         unsigned* sh_cnt, unsigned* sh_sum, int* sh_bk,
                         int& b_out, int& kr_out) {
  const int t = threadIdx.x;
  __syncthreads();
  if (t == 0) { sh_bk[0] = -1; sh_bk[1] = kwant; }
  unsigned local = 0;
  for (int j = 0; j < 8; ++j) { unsigned v = gh[t * 8 + j]; sh_cnt[t * 8 + j] = v; local += v; }
  sh_sum[t] = local;
  __syncthreads();
  unsigned S = 0;
  for (int j = t + 1; j < 256; ++j) S += sh_sum[j];
  int cand_b = -1;
  unsigned cand_above = 0;
  unsigned run = S;
  for (int j = 7; j >= 0; --j) {
    const unsigned cv = sh_cnt[t * 8 + j];
    if (cand_b < 0 && run + cv >= (unsigned)kwant) { cand_b = t * 8 + j; cand_above = run; }
    run += cv;
  }
  if (cand_b >= 0) atomicMax(&sh_bk[0], cand_b);
  __syncthreads();
  if (cand_b >= 0 && cand_b == sh_bk[0]) sh_bk[1] = kwant - (int)cand_above;
  __syncthreads();
  b_out = (sh_bk[0] < 0) ? 0 : sh_bk[0];
  kr_out = sh_bk[1];
}

// One float4 per thread over [NIMG][NCHW]; keys cached in d_out scratch.
// Blocks 0..719 -> image 0, 720..1439 -> image 1 (NCHW/1024 = 720 exactly).
__global__ __launch_bounds__(256) void k_keygen(const float* __restrict__ box_cls,
                                                const float* __restrict__ ctrness,
                                                unsigned* __restrict__ ws,
                                                uint4* __restrict__ keys) {
  __shared__ unsigned hist[2048];
  for (int i = threadIdx.x; i < 2048; i += 256) hist[i] = 0;
  __syncthreads();
  const int n = blockIdx.x >= 720;
  const int i4 = blockIdx.x * 256 + threadIdx.x;           // global float4 index
  const int i = i4 * 4;                                    // flat elem index
  const int j = i - n * NCHW;                              // offset within image
  const int c = j / NHW;
  const int hw = j - c * NHW;                              // multiple of 4
  const f4 xv = *reinterpret_cast<const f4*>(box_cls + i);
  const f4 cv = *reinterpret_cast<const f4*>(ctrness + n * NHW + hw);
  unsigned kk[4];
  #pragma unroll
  for (int q = 0; q < 4; ++q) {
    const float s = 1.0f / (1.0f + expf(-xv[q]));
    float v = -1.0f;
    if (s > PRE_THRESH) v = s * (1.0f / (1.0f + expf(-cv[q])));
    const unsigned k = key_of(v);
    kk[q] = k;
    if (k > KEY_ZERO) atomicAdd(&hist[k >> 21], 1u);       // hist positives only
  }
  keys[i4] = make_uint4(kk[0], kk[1], kk[2], kk[3]);
  __syncthreads();
  unsigned* gh = ws + WS_HIST1 + n * 2048;
  for (int t = threadIdx.x; t < 2048; t += 256) { unsigned v = hist[t]; if (v) atomicAdd(&gh[t], v); }
}

__global__ __launch_bounds__(256) void k_scan1(unsigned* __restrict__ ws) {
  __shared__ unsigned sh_cnt[2048];
  __shared__ unsigned sh_sum[256];
  __shared__ int sh_bk[2];
  const int n = blockIdx.x;
  int b1, kr;
  scan2048(ws + WS_HIST1 + n * 2048, KTOP, sh_cnt, sh_sum, sh_bk, b1, kr);
  if (threadIdx.x == 0) { ws[WS_B1 + n] = (unsigned)b1; ws[WS_KREM1 + n] = (unsigned)kr; }
}

// Compact all candidates with top-11 bucket >= b1 into ws pairs {key, ref}.
__global__ __launch_bounds__(256) void k_gather(const uint4* __restrict__ keys,
                                                unsigned* __restrict__ ws) {
  const int n = blockIdx.x >= 720;
  const unsigned b1 = ws[WS_B1 + n];
  const int i4 = blockIdx.x * 256 + threadIdx.x;
  const uint4 kv = keys[i4];
  const unsigned kk[4] = {kv.x, kv.y, kv.z, kv.w};
  #pragma unroll
  for (int q = 0; q < 4; ++q) {
    const unsigned k = kk[q];
    if ((k >> 21) < b1) continue;
    const int i = i4 * 4 + q;
    const int j = i - n * NCHW;
    const int c = j / NHW;
    const int hw = j - c * NHW;
    const unsigned ref = (unsigned)(hw * NC + c);          // reference flat order index
    const unsigned pos = atomicAdd(ws + WS_CNT + n, 1u);
    if (pos < (unsigned)CAP) {
      ws[WS_PAIRS + (n * CAP + (int)pos) * 2]     = k;
      ws[WS_PAIRS + (n * CAP + (int)pos) * 2 + 1] = ref;
    }
  }
}

// One block per image: refine 11-bit prefix by two 8-bit levels (-> 27-bit
// threshold), compact members, exact rank WITHIN members only (value desc,
// index asc = lax.top_k), build per-slot params.
__global__ __launch_bounds__(256) void k_final(unsigned* __restrict__ ws,
                                               const float* __restrict__ locations,
                                               const float* __restrict__ box_reg,
                                               const float* __restrict__ pemb,
                                               const float* __restrict__ pmar) {
  const int n = blockIdx.x;
  const int t = threadIdx.x;
  __shared__ uint2 P[CAP];             // 32 KiB
  __shared__ unsigned h256[256];
  __shared__ unsigned mKey[MCAP], mRef[MCAP];
  __shared__ int sh_b, sh_t;
  // pre-init all slots invalid
  for (int s = t; s < KTOP; s += 256) ws[WS_PARAMS + (n * KTOP + s) * PARAM_WORDS] = 0u;
  const unsigned b1 = ws[WS_B1 + n];
  int krem = (int)ws[WS_KREM1 + n];
  const int cnt = min((int)ws[WS_CNT + n], CAP);
  for (int i = t; i < cnt; i += 256) {
    P[i].x = ws[WS_PAIRS + (n * CAP + i) * 2];
    P[i].y = ws[WS_PAIRS + (n * CAP + i) * 2 + 1];
  }
  __syncthreads();

  // ---- two refine levels: prefix 11 -> 19 -> 27 bits ----
  unsigned prefix = b1;
  int shift = 21;
  #pragma unroll
  for (int level = 0; level < 2; ++level) {
    const int newshift = shift - 8;
    h256[t] = 0;
    if (t == 0) sh_b = 0;
    __syncthreads();
    for (int i = t; i < cnt; i += 256) {
      const unsigned k = P[i].x;
      if ((k >> shift) == prefix) atomicAdd(&h256[(k >> newshift) & 255u], 1u);
    }
    __syncthreads();
    const unsigned hv = h256[t];
    unsigned S = 0;                         // suffix-exclusive count for bucket t
    for (int j = t + 1; j < 256; ++j) S += h256[j];
    if (S + hv >= (unsigned)krem) atomicMax(&sh_b, t);
    __syncthreads();
    const int b = sh_b;
    if (t == b) sh_t = krem - (int)S;       // krem within chosen bucket
    __syncthreads();
    krem = sh_t;
    prefix = (prefix << 8) | (unsigned)b;
    shift = newshift;
    __syncthreads();
  }

  // ---- compact members: key >= prefix<<5 (all non-members strictly smaller) ----
  if (t == 0) sh_t = 0;
  __syncthreads();
  for (int i = t; i < cnt; i += 256) {
    const unsigned k = P[i].x;
    if ((k >> 5) >= prefix) {
      const int pos = atomicAdd(&sh_t, 1);
      if (pos < MCAP) { mKey[pos] = k; mRef[pos] = P[i].y; }
    }
  }
  __syncthreads();
  const int m = min(sh_t, MCAP);

  // ---- exact rank within members + emit ----
  for (int i = t; i < m; i += 256) {
    const unsigned ki = mKey[i], ri = mRef[i];
    int rank = 0;
    for (int j = 0; j < m; ++j) {
      const unsigned kj = mKey[j], rj = mRef[j];
      rank += (kj > ki || (kj == ki && rj < ri)) ? 1 : 0;
    }
    if (rank >= KTOP) continue;
    unsigned* pp = ws + WS_PARAMS + (n * KTOP + rank) * PARAM_WORDS;
    int valid = 0;
    if (ki > KEY_ZERO) {
      const int hw = (int)ri / NC;
      const float lx = locations[2 * hw], ly = locations[2 * hw + 1];
      const float rl = box_reg[(n * 4 + 0) * NHW + hw];
      const float rt = box_reg[(n * 4 + 1) * NHW + hw];
      const float rr = box_reg[(n * 4 + 2) * NHW + hw];
      const float rb = box_reg[(n * 4 + 3) * NHW + hw];
      const float x1 = fminf(fmaxf(lx - rl, 0.f), IMG_MAX);
      const float y1 = fminf(fmaxf(ly - rt, 0.f), IMG_MAX);
      const float x2 = fminf(fmaxf(lx + rr, 0.f), IMG_MAX);
      const float y2 = fminf(fmaxf(ly + rb, 0.f), IMG_MAX);
      const int ix0 = max(0, (int)ceilf(x1 * 0.25f));
      const int ix1 = min(OW - 1, (int)floorf(x2 * 0.25f));
      const int iy0 = max(0, (int)ceilf(y1 * 0.25f));
      const int iy1 = min(OH - 1, (int)floorf(y2 * 0.25f));
      if (ix0 <= ix1 && iy0 <= iy1) {
        valid = 1;
        pp[1] = (unsigned)ix0; pp[2] = (unsigned)ix1;
        pp[3] = (unsigned)iy0; pp[4] = (unsigned)iy1;
        reinterpret_cast<float*>(pp)[5] = pmar[n * NHW + hw];
        float* ep = reinterpret_cast<float*>(pp) + 8;
        #pragma unroll
        for (int d = 0; d < NDIM; ++d) ep[d] = pemb[(n * NDIM + d) * NHW + hw];
      }
    }
    pp[0] = (unsigned)valid;
  }
}

// Full-output streaming zero with nontemporal 16B stores.
__global__ __launch_bounds__(256) void k_zero_out(f4* __restrict__ out, int n4) {
  const f4 z = {0.f, 0.f, 0.f, 0.f};
  for (int i = blockIdx.x * 256 + threadIdx.x; i < n4; i += gridDim.x * 256)
    __builtin_nontemporal_store(z, out + i);
}

// In-box compute only: one block per (n,k). 64 columns x 4 row-strips; each
// thread walks a column with register-staged x-interpolated source rows.
__global__ __launch_bounds__(256) void k_box(const float* __restrict__ pix,
                                             const unsigned* __restrict__ ws,
                                             float* __restrict__ out) {
  const int nk = blockIdx.x;  // n*KTOP + k
  const unsigned* meta = ws + WS_PARAMS + nk * PARAM_WORDS;
  if (meta[0] == 0u) return;
  const int ix0 = (int)meta[1], ix1 = (int)meta[2];
  const int iy0 = (int)meta[3], iy1 = (int)meta[4];
  const float margin = __uint_as_float(meta[5]);
  float e[NDIM];
  {
    const float4* e4 = reinterpret_cast<const float4*>(meta + 8);
    #pragma unroll
    for (int q = 0; q < NDIM / 4; ++q) {
      const float4 v = e4[q];
      e[4 * q + 0] = v.x; e[4 * q + 1] = v.y; e[4 * q + 2] = v.z; e[4 * q + 3] = v.w;
    }
  }
  const int n = nk / KTOP;
  const float* peb = pix + (size_t)n * NDIM * PH * PW;
  float* ob = out + (size_t)nk * (OH * OW);

  const int tx = threadIdx.x & 63;   // column lane
  const int ts = threadIdx.x >> 6;   // row strip 0..3
  const int h = iy1 - iy0 + 1;
  const int shh = (h + 3) >> 2;
  const int ybeg = iy0 + ts * shh;
  const int yend = min(iy0 + (ts + 1) * shh, iy1 + 1);

  for (int c = ix0 + tx; c <= ix1; c += 64) {
    const float sx = 0.5f * (float)c - 0.25f;
    const float xf = floorf(sx);
    const float fx = sx - xf;
    const int xs0 = max((int)xf, 0);
    const int xs1 = min((int)xf + 1, PW - 1);
    float qa[NDIM], qb[NDIM];
    int ra = -9, rb = -9;
    for (int y = ybeg; y < yend; ++y) {
      const float sy = 0.5f * (float)y - 0.25f;
      const float yf = floorf(sy);
      const float fy = sy - yf;
      const int ys0 = max((int)yf, 0);
      const int ys1 = min((int)yf + 1, PH - 1);
      if (ys0 != ra) {
        if (ys0 == rb) {
          #pragma unroll
          for (int d = 0; d < NDIM; ++d) qa[d] = qb[d];
        } else {
          const float* p = peb + (size_t)ys0 * PW;
          #pragma unroll
          for (int d = 0; d < NDIM; ++d)
            qa[d] = (1.f - fx) * p[d * PH * PW + xs0] + fx * p[d * PH * PW + xs1];
        }
        ra = ys0;
      }
      if (ys1 != rb) {
        if (ys1 == ra) {
          #pragma unroll
          for (int d = 0; d < NDIM; ++d) qb[d] = qa[d];
        } else {
          const float* p = peb + (size_t)ys1 * PW;
          #pragma unroll
          for (int d = 0; d < NDIM; ++d)
            qb[d] = (1.f - fx) * p[d * PH * PW + xs0] + fx * p[d * PH * PW + xs1];
        }
        rb = ys1;
      }
      float d2 = 0.f;
      #pragma unroll
      for (int d = 0; d < NDIM; ++d) {
        const float pv = qa[d] + fy * (qb[d] - qa[d]);
        const float df = e[d] - pv;
        d2 = fmaf(df, df, d2);
      }
      ob[(size_t)y * OW + c] = expf(-d2 * margin);
    }
  }
}

extern "C" void kernel_launch(void* const* d_in, const int* in_sizes, int n_in,
                              void* d_out, int out_size, void* d_ws, size_t ws_size,
                              hipStream_t stream) {
  const float* locations = (const float*)d_in[0];
  const float* box_cls   = (const float*)d_in[1];
  const float* box_reg   = (const float*)d_in[2];
  const float* ctrness   = (const float*)d_in[3];
  const float* pemb      = (const float*)d_in[4];
  const float* pmar      = (const float*)d_in[5];
  const float* pix       = (const float*)d_in[6];
  float* out = (float*)d_out;
  unsigned* ws = (unsigned*)d_ws;
  uint4* keys = (uint4*)d_out;  // 5.9 MB scratch; overwritten by k_zero_out afterwards

  hipMemsetAsync(ws, 0, (size_t)WS_ZERO_WORDS * 4, stream);
  k_keygen<<<dim3(1440), dim3(256), 0, stream>>>(box_cls, ctrness, ws, keys);
  k_scan1 <<<dim3(NIMG), dim3(256), 0, stream>>>(ws);
  k_gather<<<dim3(1440), dim3(256), 0, stream>>>(keys, ws);
  k_final <<<dim3(NIMG), dim3(256), 0, stream>>>(ws, locations, box_reg, pemb, pmar);
  const int n4 = out_size / 4;  // 14,745,600 float4
  k_zero_out<<<dim3(4096), dim3(256), 0, stream>>>((f4*)d_out, n4);
  k_box<<<dim3(NIMG * KTOP), dim3(256), 0, stream>>>(pix, ws, out);
}

// Round 5
// 138.263 us; speedup vs baseline: 2.1239x; 1.0914x over previous
//
#include <hip/hip_runtime.h>
#include <cmath>

// EmbedMaskPostProcessor: top-k select + box decode + embedding-distance masks.
// Output [2,200,384,384] f32 = 236 MB, <1% nonzero -> write-BW bound (~36us floor).
// R5: removed in-graph hipMemsetAsync (rocclr fillBuffer node cost ~75-136us for
// 16KB!) -> own k_zero_ws kernel. k_zero_out: plain stores (harness fill hit
// 6.67 TB/s pure-write vs 4.3 for nt-stores), grid 8192.

namespace {
constexpr int NIMG = 2;
constexpr int NC   = 80;
constexpr int NHW  = 96 * 96;        // 9216
constexpr int NCHW = NC * NHW;       // 737280
constexpr int NDIM = 32;
constexpr int PH = 192, PW = 192;    // pixel_embed spatial
constexpr int OH = 384, OW = 384;    // output mask spatial
constexpr int KTOP = 200;
constexpr int CAP = 4096;            // gathered band candidates per image
constexpr int MCAP = 1024;           // member cap after 27-bit refine
constexpr float PRE_THRESH = 0.05f;
constexpr unsigned KEY_ZERO = 0x80000000u;  // key of +0.0f; key > this <=> value > 0
constexpr float IMG_MAX = 767.0f;

// ws layout (4-byte words)
constexpr int WS_HIST1  = 0;                         // [NIMG][2048]
constexpr int WS_CNT    = WS_HIST1 + NIMG * 2048;    // [NIMG] gathered count
constexpr int WS_B1     = WS_CNT + NIMG;             // [NIMG]
constexpr int WS_KREM1  = WS_B1 + NIMG;              // [NIMG]
constexpr int WS_PAIRS  = 4104;                      // [NIMG][CAP][2] {key,ref} (8B aligned)
constexpr int WS_PARAMS = WS_PAIRS + NIMG * CAP * 2; // [NIMG][KTOP][40]
constexpr int PARAM_WORDS = 40;  // [0]=valid [1..4]=ix0,ix1,iy0,iy1 [5]=margin [8..39]=e
constexpr int WS_ZERO_WORDS = WS_CNT + NIMG;         // zero range (hist + counts)

typedef float f4 __attribute__((ext_vector_type(4)));
}

__device__ __forceinline__ unsigned key_of(float f) {
  unsigned u = __float_as_uint(f);
  return (u & 0x80000000u) ? ~u : (u | 0x80000000u);  // monotone: bigger float -> bigger key
}

// Find b* = max bucket (of 2048) with suffix-count >= kwant; kr_out = kwant - count(buckets > b*).
__device__ void scan2048(const unsigned* __restrict__ gh, int kwant,
                         unsigned* sh_cnt, unsigned* sh_sum, int* sh_bk,
                         int& b_out, int& kr_out) {
  const int t = threadIdx.x;
  __syncthreads();
  if (t == 0) { sh_bk[0] = -1; sh_bk[1] = kwant; }
  unsigned local = 0;
  for (int j = 0; j < 8; ++j) { unsigned v = gh[t * 8 + j]; sh_cnt[t * 8 + j] = v; local += v; }
  sh_sum[t] = local;
  __syncthreads();
  unsigned S = 0;
  for (int j = t + 1; j < 256; ++j) S += sh_sum[j];
  int cand_b = -1;
  unsigned cand_above = 0;
  unsigned run = S;
  for (int j = 7; j >= 0; --j) {
    const unsigned cv = sh_cnt[t * 8 + j];
    if (cand_b < 0 && run + cv >= (unsigned)kwant) { cand_b = t * 8 + j; cand_above = run; }
    run += cv;
  }
  if (cand_b >= 0) atomicMax(&sh_bk[0], cand_b);
  __syncthreads();
  if (cand_b >= 0 && cand_b == sh_bk[0]) sh_bk[1] = kwant - (int)cand_above;
  __syncthreads();
  b_out = (sh_bk[0] < 0) ? 0 : sh_bk[0];
  kr_out = sh_bk[1];
}

// Zero the hist/counter words (replaces rocclr fill node).
__global__ __launch_bounds__(256) void k_zero_ws(unsigned* __restrict__ ws) {
  const int i = blockIdx.x * 256 + threadIdx.x;
  for (int j = i; j < WS_ZERO_WORDS; j += 8 * 256) ws[j] = 0u;
}

// One float4 per thread over [NIMG][NCHW]; keys cached in d_out scratch.
// Blocks 0..719 -> image 0, 720..1439 -> image 1 (NCHW/1024 = 720 exactly).
__global__ __launch_bounds__(256) void k_keygen(const float* __restrict__ box_cls,
                                                const float* __restrict__ ctrness,
                                                unsigned* __restrict__ ws,
                                                uint4* __restrict__ keys) {
  __shared__ unsigned hist[2048];
  for (int i = threadIdx.x; i < 2048; i += 256) hist[i] = 0;
  __syncthreads();
  const int n = blockIdx.x >= 720;
  const int i4 = blockIdx.x * 256 + threadIdx.x;           // global float4 index
  const int i = i4 * 4;                                    // flat elem index
  const int j = i - n * NCHW;                              // offset within image
  const int c = j / NHW;
  const int hw = j - c * NHW;                              // multiple of 4
  const f4 xv = *reinterpret_cast<const f4*>(box_cls + i);
  const f4 cv = *reinterpret_cast<const f4*>(ctrness + n * NHW + hw);
  unsigned kk[4];
  #pragma unroll
  for (int q = 0; q < 4; ++q) {
    const float s = 1.0f / (1.0f + expf(-xv[q]));
    float v = -1.0f;
    if (s > PRE_THRESH) v = s * (1.0f / (1.0f + expf(-cv[q])));
    const unsigned k = key_of(v);
    kk[q] = k;
    if (k > KEY_ZERO) atomicAdd(&hist[k >> 21], 1u);       // hist positives only
  }
  keys[i4] = make_uint4(kk[0], kk[1], kk[2], kk[3]);
  __syncthreads();
  unsigned* gh = ws + WS_HIST1 + n * 2048;
  for (int t = threadIdx.x; t < 2048; t += 256) { unsigned v = hist[t]; if (v) atomicAdd(&gh[t], v); }
}

__global__ __launch_bounds__(256) void k_scan1(unsigned* __restrict__ ws) {
  __shared__ unsigned sh_cnt[2048];
  __shared__ unsigned sh_sum[256];
  __shared__ int sh_bk[2];
  const int n = blockIdx.x;
  int b1, kr;
  scan2048(ws + WS_HIST1 + n * 2048, KTOP, sh_cnt, sh_sum, sh_bk, b1, kr);
  if (threadIdx.x == 0) { ws[WS_B1 + n] = (unsigned)b1; ws[WS_KREM1 + n] = (unsigned)kr; }
}

// Compact all candidates with top-11 bucket >= b1 into ws pairs {key, ref}.
__global__ __launch_bounds__(256) void k_gather(const uint4* __restrict__ keys,
                                                unsigned* __restrict__ ws) {
  const int n = blockIdx.x >= 720;
  const unsigned b1 = ws[WS_B1 + n];
  const int i4 = blockIdx.x * 256 + threadIdx.x;
  const uint4 kv = keys[i4];
  const unsigned kk[4] = {kv.x, kv.y, kv.z, kv.w};
  #pragma unroll
  for (int q = 0; q < 4; ++q) {
    const unsigned k = kk[q];
    if ((k >> 21) < b1) continue;
    const int i = i4 * 4 + q;
    const int j = i - n * NCHW;
    const int c = j / NHW;
    const int hw = j - c * NHW;
    const unsigned ref = (unsigned)(hw * NC + c);          // reference flat order index
    const unsigned pos = atomicAdd(ws + WS_CNT + n, 1u);
    if (pos < (unsigned)CAP) {
      ws[WS_PAIRS + (n * CAP + (int)pos) * 2]     = k;
      ws[WS_PAIRS + (n * CAP + (int)pos) * 2 + 1] = ref;
    }
  }
}

// One block per image: refine 11-bit prefix by two 8-bit levels (-> 27-bit
// threshold), compact members, exact rank WITHIN members only (value desc,
// index asc = lax.top_k), build per-slot params.
__global__ __launch_bounds__(256) void k_final(unsigned* __restrict__ ws,
                                               const float* __restrict__ locations,
                                               const float* __restrict__ box_reg,
                                               const float* __restrict__ pemb,
                                               const float* __restrict__ pmar) {
  const int n = blockIdx.x;
  const int t = threadIdx.x;
  __shared__ uint2 P[CAP];             // 32 KiB
  __shared__ unsigned h256[256];
  __shared__ unsigned mKey[MCAP], mRef[MCAP];
  __shared__ int sh_b, sh_t;
  // pre-init all slots invalid
  for (int s = t; s < KTOP; s += 256) ws[WS_PARAMS + (n * KTOP + s) * PARAM_WORDS] = 0u;
  const unsigned b1 = ws[WS_B1 + n];
  int krem = (int)ws[WS_KREM1 + n];
  const int cnt = min((int)ws[WS_CNT + n], CAP);
  for (int i = t; i < cnt; i += 256) {
    P[i].x = ws[WS_PAIRS + (n * CAP + i) * 2];
    P[i].y = ws[WS_PAIRS + (n * CAP + i) * 2 + 1];
  }
  __syncthreads();

  // ---- two refine levels: prefix 11 -> 19 -> 27 bits ----
  unsigned prefix = b1;
  int shift = 21;
  #pragma unroll
  for (int level = 0; level < 2; ++level) {
    const int newshift = shift - 8;
    h256[t] = 0;
    if (t == 0) sh_b = 0;
    __syncthreads();
    for (int i = t; i < cnt; i += 256) {
      const unsigned k = P[i].x;
      if ((k >> shift) == prefix) atomicAdd(&h256[(k >> newshift) & 255u], 1u);
    }
    __syncthreads();
    const unsigned hv = h256[t];
    unsigned S = 0;                         // suffix-exclusive count for bucket t
    for (int j = t + 1; j < 256; ++j) S += h256[j];
    if (S + hv >= (unsigned)krem) atomicMax(&sh_b, t);
    __syncthreads();
    const int b = sh_b;
    if (t == b) sh_t = krem - (int)S;       // krem within chosen bucket
    __syncthreads();
    krem = sh_t;
    prefix = (prefix << 8) | (unsigned)b;
    shift = newshift;
    __syncthreads();
  }

  // ---- compact members: key >= prefix<<5 (all non-members strictly smaller) ----
  if (t == 0) sh_t = 0;
  __syncthreads();
  for (int i = t; i < cnt; i += 256) {
    const unsigned k = P[i].x;
    if ((k >> 5) >= prefix) {
      const int pos = atomicAdd(&sh_t, 1);
      if (pos < MCAP) { mKey[pos] = k; mRef[pos] = P[i].y; }
    }
  }
  __syncthreads();
  const int m = min(sh_t, MCAP);

  // ---- exact rank within members + emit ----
  for (int i = t; i < m; i += 256) {
    const unsigned ki = mKey[i], ri = mRef[i];
    int rank = 0;
    for (int j = 0; j < m; ++j) {
      const unsigned kj = mKey[j], rj = mRef[j];
      rank += (kj > ki || (kj == ki && rj < ri)) ? 1 : 0;
    }
    if (rank >= KTOP) continue;
    unsigned* pp = ws + WS_PARAMS + (n * KTOP + rank) * PARAM_WORDS;
    int valid = 0;
    if (ki > KEY_ZERO) {
      const int hw = (int)ri / NC;
      const float lx = locations[2 * hw], ly = locations[2 * hw + 1];
      const float rl = box_reg[(n * 4 + 0) * NHW + hw];
      const float rt = box_reg[(n * 4 + 1) * NHW + hw];
      const float rr = box_reg[(n * 4 + 2) * NHW + hw];
      const float rb = box_reg[(n * 4 + 3) * NHW + hw];
      const float x1 = fminf(fmaxf(lx - rl, 0.f), IMG_MAX);
      const float y1 = fminf(fmaxf(ly - rt, 0.f), IMG_MAX);
      const float x2 = fminf(fmaxf(lx + rr, 0.f), IMG_MAX);
      const float y2 = fminf(fmaxf(ly + rb, 0.f), IMG_MAX);
      const int ix0 = max(0, (int)ceilf(x1 * 0.25f));
      const int ix1 = min(OW - 1, (int)floorf(x2 * 0.25f));
      const int iy0 = max(0, (int)ceilf(y1 * 0.25f));
      const int iy1 = min(OH - 1, (int)floorf(y2 * 0.25f));
      if (ix0 <= ix1 && iy0 <= iy1) {
        valid = 1;
        pp[1] = (unsigned)ix0; pp[2] = (unsigned)ix1;
        pp[3] = (unsigned)iy0; pp[4] = (unsigned)iy1;
        reinterpret_cast<float*>(pp)[5] = pmar[n * NHW + hw];
        float* ep = reinterpret_cast<float*>(pp) + 8;
        #pragma unroll
        for (int d = 0; d < NDIM; ++d) ep[d] = pemb[(n * NDIM + d) * NHW + hw];
      }
    }
    pp[0] = (unsigned)valid;
  }
}

// Full-output streaming zero. Plain stores (L2 write-combine drains at ~6.6 TB/s
// per the harness's own fillBuffer; nt-stores measured slower at ~4.3).
__global__ __launch_bounds__(256) void k_zero_out(f4* __restrict__ out, int n4) {
  const f4 z = {0.f, 0.f, 0.f, 0.f};
  for (int i = blockIdx.x * 256 + threadIdx.x; i < n4; i += gridDim.x * 256)
    out[i] = z;
}

// In-box compute only: one block per (n,k). 64 columns x 4 row-strips; each
// thread walks a column with register-staged x-interpolated source rows.
__global__ __launch_bounds__(256) void k_box(const float* __restrict__ pix,
                                             const unsigned* __restrict__ ws,
                                             float* __restrict__ out) {
  const int nk = blockIdx.x;  // n*KTOP + k
  const unsigned* meta = ws + WS_PARAMS + nk * PARAM_WORDS;
  if (meta[0] == 0u) return;
  const int ix0 = (int)meta[1], ix1 = (int)meta[2];
  const int iy0 = (int)meta[3], iy1 = (int)meta[4];
  const float margin = __uint_as_float(meta[5]);
  float e[NDIM];
  {
    const float4* e4 = reinterpret_cast<const float4*>(meta + 8);
    #pragma unroll
    for (int q = 0; q < NDIM / 4; ++q) {
      const float4 v = e4[q];
      e[4 * q + 0] = v.x; e[4 * q + 1] = v.y; e[4 * q + 2] = v.z; e[4 * q + 3] = v.w;
    }
  }
  const int n = nk / KTOP;
  const float* peb = pix + (size_t)n * NDIM * PH * PW;
  float* ob = out + (size_t)nk * (OH * OW);

  const int tx = threadIdx.x & 63;   // column lane
  const int ts = threadIdx.x >> 6;   // row strip 0..3
  const int h = iy1 - iy0 + 1;
  const int shh = (h + 3) >> 2;
  const int ybeg = iy0 + ts * shh;
  const int yend = min(iy0 + (ts + 1) * shh, iy1 + 1);

  for (int c = ix0 + tx; c <= ix1; c += 64) {
    const float sx = 0.5f * (float)c - 0.25f;
    const float xf = floorf(sx);
    const float fx = sx - xf;
    const int xs0 = max((int)xf, 0);
    const int xs1 = min((int)xf + 1, PW - 1);
    float qa[NDIM], qb[NDIM];
    int ra = -9, rb = -9;
    for (int y = ybeg; y < yend; ++y) {
      const float sy = 0.5f * (float)y - 0.25f;
      const float yf = floorf(sy);
      const float fy = sy - yf;
      const int ys0 = max((int)yf, 0);
      const int ys1 = min((int)yf + 1, PH - 1);
      if (ys0 != ra) {
        if (ys0 == rb) {
          #pragma unroll
          for (int d = 0; d < NDIM; ++d) qa[d] = qb[d];
        } else {
          const float* p = peb + (size_t)ys0 * PW;
          #pragma unroll
          for (int d = 0; d < NDIM; ++d)
            qa[d] = (1.f - fx) * p[d * PH * PW + xs0] + fx * p[d * PH * PW + xs1];
        }
        ra = ys0;
      }
      if (ys1 != rb) {
        if (ys1 == ra) {
          #pragma unroll
          for (int d = 0; d < NDIM; ++d) qb[d] = qa[d];
        } else {
          const float* p = peb + (size_t)ys1 * PW;
          #pragma unroll
          for (int d = 0; d < NDIM; ++d)
            qb[d] = (1.f - fx) * p[d * PH * PW + xs0] + fx * p[d * PH * PW + xs1];
        }
        rb = ys1;
      }
      float d2 = 0.f;
      #pragma unroll
      for (int d = 0; d < NDIM; ++d) {
        const float pv = qa[d] + fy * (qb[d] - qa[d]);
        const float df = e[d] - pv;
        d2 = fmaf(df, df, d2);
      }
      ob[(size_t)y * OW + c] = expf(-d2 * margin);
    }
  }
}

extern "C" void kernel_launch(void* const* d_in, const int* in_sizes, int n_in,
                              void* d_out, int out_size, void* d_ws, size_t ws_size,
                              hipStream_t stream) {
  const float* locations = (const float*)d_in[0];
  const float* box_cls   = (const float*)d_in[1];
  const float* box_reg   = (const float*)d_in[2];
  const float* ctrness   = (const float*)d_in[3];
  const float* pemb      = (const float*)d_in[4];
  const float* pmar      = (const float*)d_in[5];
  const float* pix       = (const float*)d_in[6];
  float* out = (float*)d_out;
  unsigned* ws = (unsigned*)d_ws;
  uint4* keys = (uint4*)d_out;  // 5.9 MB scratch; overwritten by k_zero_out afterwards

  k_zero_ws<<<dim3(8), dim3(256), 0, stream>>>(ws);
  k_keygen<<<dim3(1440), dim3(256), 0, stream>>>(box_cls, ctrness, ws, keys);
  k_scan1 <<<dim3(NIMG), dim3(256), 0, stream>>>(ws);
  k_gather<<<dim3(1440), dim3(256), 0, stream>>>(keys, ws);
  k_final <<<dim3(NIMG), dim3(256), 0, stream>>>(ws, locations, box_reg, pemb, pmar);
  const int n4 = out_size / 4;  // 14,745,600 float4
  k_zero_out<<<dim3(8192), dim3(256), 0, stream>>>((f4*)d_out, n4);
  k_box<<<dim3(NIMG * KTOP), dim3(256), 0, stream>>>(pix, ws, out);
}

// Round 6
// 132.948 us; speedup vs baseline: 2.2088x; 1.0400x over previous
//
#include <hip/hip_runtime.h>
#include <cmath>

// EmbedMaskPostProcessor: top-k select + box decode + embedding-distance masks.
// Output [2,200,384,384] f32 = 236 MB, <1% nonzero -> write-BW bound (~36us floor).
// R6: node-count reduction (graph per-node overhead measured ~8-11us):
//   7 nodes -> 5: scan folded into gather/final; zero+box fused into one k_out
//   with disjoint write ownership (zero blocks skip exactly the padded box f4s,
//   box blocks write the padded region incl. zero padding).

namespace {
constexpr int NIMG = 2;
constexpr int NC   = 80;
constexpr int NHW  = 96 * 96;        // 9216
constexpr int NCHW = NC * NHW;       // 737280
constexpr int NDIM = 32;
constexpr int PH = 192, PW = 192;    // pixel_embed spatial
constexpr int OH = 384, OW = 384;    // output mask spatial
constexpr int KTOP = 200;
constexpr int CAP = 4096;            // gathered band candidates per image
constexpr int MCAP = 1024;           // member cap after 27-bit refine
constexpr float PRE_THRESH = 0.05f;
constexpr unsigned KEY_ZERO = 0x80000000u;  // key of +0.0f; key > this <=> value > 0
constexpr float IMG_MAX = 767.0f;

constexpr int ZTILES = 6;            // 64-row zero tiles per (n,k)
constexpr int NZB = NIMG * KTOP * ZTILES;  // 2400 zero blocks

// ws layout (4-byte words)
constexpr int WS_HIST1  = 0;                         // [NIMG][2048]
constexpr int WS_CNT    = WS_HIST1 + NIMG * 2048;    // [NIMG] gathered count
constexpr int WS_PAIRS  = 4104;                      // [NIMG][CAP][2] {key,ref} (8B aligned)
constexpr int WS_PARAMS = WS_PAIRS + NIMG * CAP * 2; // [NIMG][KTOP][40]
constexpr int PARAM_WORDS = 40;  // [0]=valid [1..4]=ix0,ix1,iy0,iy1 [5]=margin [8..39]=e
constexpr int WS_ZERO_WORDS = WS_CNT + NIMG;         // zero range (hist + counts)

typedef float f4 __attribute__((ext_vector_type(4)));
}

__device__ __forceinline__ unsigned key_of(float f) {
  unsigned u = __float_as_uint(f);
  return (u & 0x80000000u) ? ~u : (u | 0x80000000u);  // monotone: bigger float -> bigger key
}

// Find b* = max bucket (of 2048) with suffix-count >= kwant; kr_out = kwant - count(buckets > b*).
// All 256 threads must call. Deterministic (pure integer) -> identical across blocks.
__device__ void scan2048(const unsigned* __restrict__ gh, int kwant,
                         unsigned* sh_cnt, unsigned* sh_sum, int* sh_bk,
                         int& b_out, int& kr_out) {
  const int t = threadIdx.x;
  __syncthreads();
  if (t == 0) { sh_bk[0] = -1; sh_bk[1] = kwant; }
  unsigned local = 0;
  for (int j = 0; j < 8; ++j) { unsigned v = gh[t * 8 + j]; sh_cnt[t * 8 + j] = v; local += v; }
  sh_sum[t] = local;
  __syncthreads();
  unsigned S = 0;
  for (int j = t + 1; j < 256; ++j) S += sh_sum[j];
  int cand_b = -1;
  unsigned cand_above = 0;
  unsigned run = S;
  for (int j = 7; j >= 0; --j) {
    const unsigned cv = sh_cnt[t * 8 + j];
    if (cand_b < 0 && run + cv >= (unsigned)kwant) { cand_b = t * 8 + j; cand_above = run; }
    run += cv;
  }
  if (cand_b >= 0) atomicMax(&sh_bk[0], cand_b);
  __syncthreads();
  if (cand_b >= 0 && cand_b == sh_bk[0]) sh_bk[1] = kwant - (int)cand_above;
  __syncthreads();
  b_out = (sh_bk[0] < 0) ? 0 : sh_bk[0];
  kr_out = sh_bk[1];
}

// Zero the hist/counter words.
__global__ __launch_bounds__(256) void k_zero_ws(unsigned* __restrict__ ws) {
  const int i = blockIdx.x * 256 + threadIdx.x;
  for (int j = i; j < WS_ZERO_WORDS; j += 8 * 256) ws[j] = 0u;
}

// One float4 per thread over [NIMG][NCHW]; keys cached in d_out scratch.
// Blocks 0..719 -> image 0, 720..1439 -> image 1 (NCHW/1024 = 720 exactly).
__global__ __launch_bounds__(256) void k_keygen(const float* __restrict__ box_cls,
                                                const float* __restrict__ ctrness,
                                                unsigned* __restrict__ ws,
                                                uint4* __restrict__ keys) {
  __shared__ unsigned hist[2048];
  for (int i = threadIdx.x; i < 2048; i += 256) hist[i] = 0;
  __syncthreads();
  const int n = blockIdx.x >= 720;
  const int i4 = blockIdx.x * 256 + threadIdx.x;           // global float4 index
  const int i = i4 * 4;                                    // flat elem index
  const int j = i - n * NCHW;                              // offset within image
  const int c = j / NHW;
  const int hw = j - c * NHW;                              // multiple of 4
  const f4 xv = *reinterpret_cast<const f4*>(box_cls + i);
  const f4 cv = *reinterpret_cast<const f4*>(ctrness + n * NHW + hw);
  unsigned kk[4];
  #pragma unroll
  for (int q = 0; q < 4; ++q) {
    const float s = 1.0f / (1.0f + expf(-xv[q]));
    float v = -1.0f;
    if (s > PRE_THRESH) v = s * (1.0f / (1.0f + expf(-cv[q])));
    const unsigned k = key_of(v);
    kk[q] = k;
    if (k > KEY_ZERO) atomicAdd(&hist[k >> 21], 1u);       // hist positives only
  }
  keys[i4] = make_uint4(kk[0], kk[1], kk[2], kk[3]);
  __syncthreads();
  unsigned* gh = ws + WS_HIST1 + n * 2048;
  for (int t = threadIdx.x; t < 2048; t += 256) { unsigned v = hist[t]; if (v) atomicAdd(&gh[t], v); }
}

// Compact all candidates with top-11 bucket >= b1 into ws pairs {key, ref}.
// Each block re-derives b1 from the global hist (scan folded in; no scan node).
__global__ __launch_bounds__(256) void k_gather(const uint4* __restrict__ keys,
                                                unsigned* __restrict__ ws) {
  __shared__ unsigned sh_cnt[2048];
  __shared__ unsigned sh_sum[256];
  __shared__ int sh_bk[2];
  const int n = blockIdx.x >= 720;
  int b1i, kr;
  scan2048(ws + WS_HIST1 + n * 2048, KTOP, sh_cnt, sh_sum, sh_bk, b1i, kr);
  const unsigned b1 = (unsigned)b1i;
  const int i4 = blockIdx.x * 256 + threadIdx.x;
  const uint4 kv = keys[i4];
  const unsigned kk[4] = {kv.x, kv.y, kv.z, kv.w};
  #pragma unroll
  for (int q = 0; q < 4; ++q) {
    const unsigned k = kk[q];
    if ((k >> 21) < b1) continue;
    const int i = i4 * 4 + q;
    const int j = i - n * NCHW;
    const int c = j / NHW;
    const int hw = j - c * NHW;
    const unsigned ref = (unsigned)(hw * NC + c);          // reference flat order index
    const unsigned pos = atomicAdd(ws + WS_CNT + n, 1u);
    if (pos < (unsigned)CAP) {
      ws[WS_PAIRS + (n * CAP + (int)pos) * 2]     = k;
      ws[WS_PAIRS + (n * CAP + (int)pos) * 2 + 1] = ref;
    }
  }
}

// One block per image: re-derive b1/krem, refine prefix by two 8-bit levels
// (-> 27-bit threshold), compact members, exact rank WITHIN members (value
// desc, index asc = lax.top_k), build per-slot params.
__global__ __launch_bounds__(256) void k_final(unsigned* __restrict__ ws,
                                               const float* __restrict__ locations,
                                               const float* __restrict__ box_reg,
                                               const float* __restrict__ pemb,
                                               const float* __restrict__ pmar) {
  const int n = blockIdx.x;
  const int t = threadIdx.x;
  __shared__ unsigned sh_cnt[2048];    // scan scratch, 8 KiB
  __shared__ unsigned sh_sum[256];
  __shared__ int sh_bk[2];
  __shared__ uint2 P[CAP];             // 32 KiB
  __shared__ unsigned h256[256];
  __shared__ unsigned mKey[MCAP], mRef[MCAP];
  __shared__ int sh_b, sh_t;
  // pre-init all slots invalid
  for (int s = t; s < KTOP; s += 256) ws[WS_PARAMS + (n * KTOP + s) * PARAM_WORDS] = 0u;
  int b1i, krem;
  scan2048(ws + WS_HIST1 + n * 2048, KTOP, sh_cnt, sh_sum, sh_bk, b1i, krem);
  const unsigned b1 = (unsigned)b1i;
  const int cnt = min((int)ws[WS_CNT + n], CAP);
  for (int i = t; i < cnt; i += 256) {
    P[i].x = ws[WS_PAIRS + (n * CAP + i) * 2];
    P[i].y = ws[WS_PAIRS + (n * CAP + i) * 2 + 1];
  }
  __syncthreads();

  // ---- two refine levels: prefix 11 -> 19 -> 27 bits ----
  unsigned prefix = b1;
  int shift = 21;
  #pragma unroll
  for (int level = 0; level < 2; ++level) {
    const int newshift = shift - 8;
    h256[t] = 0;
    if (t == 0) sh_b = 0;
    __syncthreads();
    for (int i = t; i < cnt; i += 256) {
      const unsigned k = P[i].x;
      if ((k >> shift) == prefix) atomicAdd(&h256[(k >> newshift) & 255u], 1u);
    }
    __syncthreads();
    const unsigned hv = h256[t];
    unsigned S = 0;                         // suffix-exclusive count for bucket t
    for (int j = t + 1; j < 256; ++j) S += h256[j];
    if (S + hv >= (unsigned)krem) atomicMax(&sh_b, t);
    __syncthreads();
    const int b = sh_b;
    if (t == b) sh_t = krem - (int)S;       // krem within chosen bucket
    __syncthreads();
    krem = sh_t;
    prefix = (prefix << 8) | (unsigned)b;
    shift = newshift;
    __syncthreads();
  }

  // ---- compact members: key >= prefix<<5 (all non-members strictly smaller) ----
  if (t == 0) sh_t = 0;
  __syncthreads();
  for (int i = t; i < cnt; i += 256) {
    const unsigned k = P[i].x;
    if ((k >> 5) >= prefix) {
      const int pos = atomicAdd(&sh_t, 1);
      if (pos < MCAP) { mKey[pos] = k; mRef[pos] = P[i].y; }
    }
  }
  __syncthreads();
  const int m = min(sh_t, MCAP);

  // ---- exact rank within members + emit ----
  for (int i = t; i < m; i += 256) {
    const unsigned ki = mKey[i], ri = mRef[i];
    int rank = 0;
    for (int j = 0; j < m; ++j) {
      const unsigned kj = mKey[j], rj = mRef[j];
      rank += (kj > ki || (kj == ki && rj < ri)) ? 1 : 0;
    }
    if (rank >= KTOP) continue;
    unsigned* pp = ws + WS_PARAMS + (n * KTOP + rank) * PARAM_WORDS;
    int valid = 0;
    if (ki > KEY_ZERO) {
      const int hw = (int)ri / NC;
      const float lx = locations[2 * hw], ly = locations[2 * hw + 1];
      const float rl = box_reg[(n * 4 + 0) * NHW + hw];
      const float rt = box_reg[(n * 4 + 1) * NHW + hw];
      const float rr = box_reg[(n * 4 + 2) * NHW + hw];
      const float rb = box_reg[(n * 4 + 3) * NHW + hw];
      const float x1 = fminf(fmaxf(lx - rl, 0.f), IMG_MAX);
      const float y1 = fminf(fmaxf(ly - rt, 0.f), IMG_MAX);
      const float x2 = fminf(fmaxf(lx + rr, 0.f), IMG_MAX);
      const float y2 = fminf(fmaxf(ly + rb, 0.f), IMG_MAX);
      const int ix0 = max(0, (int)ceilf(x1 * 0.25f));
      const int ix1 = min(OW - 1, (int)floorf(x2 * 0.25f));
      const int iy0 = max(0, (int)ceilf(y1 * 0.25f));
      const int iy1 = min(OH - 1, (int)floorf(y2 * 0.25f));
      if (ix0 <= ix1 && iy0 <= iy1) {
        valid = 1;
        pp[1] = (unsigned)ix0; pp[2] = (unsigned)ix1;
        pp[3] = (unsigned)iy0; pp[4] = (unsigned)iy1;
        reinterpret_cast<float*>(pp)[5] = pmar[n * NHW + hw];
        float* ep = reinterpret_cast<float*>(pp) + 8;
        #pragma unroll
        for (int d = 0; d < NDIM; ++d) ep[d] = pemb[(n * NDIM + d) * NHW + hw];
      }
    }
    pp[0] = (unsigned)valid;
  }
}

// Fused output kernel, disjoint write ownership:
//  blocks [0, NZB): zero tiles (nk = b/6, 64 rows each), skipping exactly the
//    padded-box f4 range [qa,qb] x [iy0,iy1] of their nk.
//  blocks [NZB, NZB+400): box compute over the padded f4-aligned region,
//    writing exp(-d2*margin) inside the box and 0.0 on the f4 padding.
__global__ __launch_bounds__(256) void k_out(const float* __restrict__ pix,
                                             const unsigned* __restrict__ ws,
                                             float* __restrict__ out) {
  const int bid = blockIdx.x;
  const int t = threadIdx.x;
  if (bid < NZB) {
    const int nk = bid / ZTILES;
    const int rt = bid - nk * ZTILES;
    const int y0 = rt * 64;
    const unsigned* meta = ws + WS_PARAMS + nk * PARAM_WORDS;
    f4* ob4 = reinterpret_cast<f4*>(out + (size_t)nk * (OH * OW)) + y0 * (OW / 4);
    const f4 z = {0.f, 0.f, 0.f, 0.f};
    int qa = 0, qb = -1, iy0 = 0, iy1 = -1;
    bool overlap = false;
    if (meta[0]) {
      iy0 = (int)meta[3]; iy1 = (int)meta[4];
      if (iy1 >= y0 && iy0 < y0 + 64) {
        overlap = true;
        qa = (int)meta[1] >> 2;
        qb = (int)meta[2] >> 2;
      }
    }
    if (!overlap) {                      // fast path: 24 contiguous f4 stores/thread
      #pragma unroll
      for (int i = 0; i < 24; ++i) ob4[i * 256 + t] = z;
    } else {
      for (int i = 0; i < 24; ++i) {
        const int idx = i * 256 + t;
        const int y = y0 + idx / 96;
        const int q = idx - (idx / 96) * 96;
        if (y >= iy0 && y <= iy1 && q >= qa && q <= qb) continue;  // box block owns
        ob4[idx] = z;
      }
    }
    return;
  }

  // ---- box compute path ----
  const int nk = bid - NZB;
  const unsigned* meta = ws + WS_PARAMS + nk * PARAM_WORDS;
  if (meta[0] == 0u) return;
  const int ix0 = (int)meta[1], ix1 = (int)meta[2];
  const int iy0 = (int)meta[3], iy1 = (int)meta[4];
  const int xp0 = (ix0 >> 2) << 2;         // padded f4-aligned column range
  const int xp1 = (ix1 >> 2) * 4 + 3;
  const float margin = __uint_as_float(meta[5]);
  float e[NDIM];
  {
    const float4* e4 = reinterpret_cast<const float4*>(meta + 8);
    #pragma unroll
    for (int q = 0; q < NDIM / 4; ++q) {
      const float4 v = e4[q];
      e[4 * q + 0] = v.x; e[4 * q + 1] = v.y; e[4 * q + 2] = v.z; e[4 * q + 3] = v.w;
    }
  }
  const int n = nk / KTOP;
  const float* peb = pix + (size_t)n * NDIM * PH * PW;
  float* ob = out + (size_t)nk * (OH * OW);

  const int tx = t & 63;             // column lane
  const int ts = t >> 6;             // row strip 0..3
  const int h = iy1 - iy0 + 1;
  const int shh = (h + 3) >> 2;
  const int ybeg = iy0 + ts * shh;
  const int yend = min(iy0 + (ts + 1) * shh, iy1 + 1);

  for (int c = xp0 + tx; c <= xp1; c += 64) {
    const bool inx = (c >= ix0) && (c <= ix1);
    const float sx = 0.5f * (float)c - 0.25f;
    const float xf = floorf(sx);
    const float fx = sx - xf;
    const int xs0 = max((int)xf, 0);
    const int xs1 = min((int)xf + 1, PW - 1);
    float qa_[NDIM], qb_[NDIM];
    int ra = -9, rb = -9;
    for (int y = ybeg; y < yend; ++y) {
      float val = 0.f;
      if (inx) {
        const float sy = 0.5f * (float)y - 0.25f;
        const float yf = floorf(sy);
        const float fy = sy - yf;
        const int ys0 = max((int)yf, 0);
        const int ys1 = min((int)yf + 1, PH - 1);
        if (ys0 != ra) {
          if (ys0 == rb) {
            #pragma unroll
            for (int d = 0; d < NDIM; ++d) qa_[d] = qb_[d];
          } else {
            const float* p = peb + (size_t)ys0 * PW;
            #pragma unroll
            for (int d = 0; d < NDIM; ++d)
              qa_[d] = (1.f - fx) * p[d * PH * PW + xs0] + fx * p[d * PH * PW + xs1];
          }
          ra = ys0;
        }
        if (ys1 != rb) {
          if (ys1 == ra) {
            #pragma unroll
            for (int d = 0; d < NDIM; ++d) qb_[d] = qa_[d];
          } else {
            const float* p = peb + (size_t)ys1 * PW;
            #pragma unroll
            for (int d = 0; d < NDIM; ++d)
              qb_[d] = (1.f - fx) * p[d * PH * PW + xs0] + fx * p[d * PH * PW + xs1];
          }
          rb = ys1;
        }
        float d2 = 0.f;
        #pragma unroll
        for (int d = 0; d < NDIM; ++d) {
          const float pv = qa_[d] + fy * (qb_[d] - qa_[d]);
          const float df = e[d] - pv;
          d2 = fmaf(df, df, d2);
        }
        val = expf(-d2 * margin);
      }
      ob[(size_t)y * OW + c] = val;
    }
  }
}

extern "C" void kernel_launch(void* const* d_in, const int* in_sizes, int n_in,
                              void* d_out, int out_size, void* d_ws, size_t ws_size,
                              hipStream_t stream) {
  const float* locations = (const float*)d_in[0];
  const float* box_cls   = (const float*)d_in[1];
  const float* box_reg   = (const float*)d_in[2];
  const float* ctrness   = (const float*)d_in[3];
  const float* pemb      = (const float*)d_in[4];
  const float* pmar      = (const float*)d_in[5];
  const float* pix       = (const float*)d_in[6];
  float* out = (float*)d_out;
  unsigned* ws = (unsigned*)d_ws;
  uint4* keys = (uint4*)d_out;  // 5.9 MB scratch; fully overwritten by k_out

  k_zero_ws<<<dim3(8), dim3(256), 0, stream>>>(ws);
  k_keygen <<<dim3(1440), dim3(256), 0, stream>>>(box_cls, ctrness, ws, keys);
  k_gather <<<dim3(1440), dim3(256), 0, stream>>>(keys, ws);
  k_final  <<<dim3(NIMG), dim3(256), 0, stream>>>(ws, locations, box_reg, pemb, pmar);
  k_out    <<<dim3(NZB + NIMG * KTOP), dim3(256), 0, stream>>>(pix, ws, out);
}

// Round 7
// 107.959 us; speedup vs baseline: 2.7200x; 1.2315x over previous
//
#include <hip/hip_runtime.h>
#include <cmath>

// EmbedMaskPostProcessor: top-k select + box decode + embedding-distance masks.
// Output [2,200,384,384] f32 = 236 MB, <1% nonzero -> write-BW bound (~34us floor).
// R7: atomic-chain elimination. ~83% of candidates pass the 0.05 threshold ->
// ~612K positive keys/img in ~80 hot 11-bit buckets. Chains were:
//   keygen hist flush: 1440 blocks/bucket -> now 128 (grid-stride, 256 blocks)
//   gather global count: ~3000 same-word adds -> 1 per block (LDS two-phase)

namespace {
constexpr int NIMG = 2;
constexpr int NC   = 80;
constexpr int NHW  = 96 * 96;        // 9216
constexpr int NCHW = NC * NHW;       // 737280
constexpr int NDIM = 32;
constexpr int PH = 192, PW = 192;    // pixel_embed spatial
constexpr int OH = 384, OW = 384;    // output mask spatial
constexpr int KTOP = 200;
constexpr int CAP = 4096;            // gathered band candidates per image
constexpr int MCAP = 1024;           // member cap after 27-bit refine
constexpr float PRE_THRESH = 0.05f;
constexpr unsigned KEY_ZERO = 0x80000000u;  // key of +0.0f; key > this <=> value > 0
constexpr float IMG_MAX = 767.0f;

constexpr int ZTILES = 6;            // 64-row zero tiles per (n,k)
constexpr int NZB = NIMG * KTOP * ZTILES;  // 2400 zero blocks

constexpr int NF4 = NCHW / 4;        // 184320 float4 per image
constexpr int SEL_BLOCKS = 128;      // selection blocks per image
constexpr int SEL_STRIDE = SEL_BLOCKS * 256;               // 32768 f4 per sweep step
constexpr int SEL_ITERS = (NF4 + SEL_STRIDE - 1) / SEL_STRIDE;  // 6
constexpr int LCAP = 512;            // per-block gather buffer (band ~4K scattered / 128 blocks)

// ws layout (4-byte words)
constexpr int WS_HIST1  = 0;                         // [NIMG][2048]
constexpr int WS_CNT    = WS_HIST1 + NIMG * 2048;    // [NIMG] gathered count
constexpr int WS_PAIRS  = 4104;                      // [NIMG][CAP][2] {key,ref} (8B aligned)
constexpr int WS_PARAMS = WS_PAIRS + NIMG * CAP * 2; // [NIMG][KTOP][40]
constexpr int PARAM_WORDS = 40;  // [0]=valid [1..4]=ix0,ix1,iy0,iy1 [5]=margin [8..39]=e
constexpr int WS_ZERO_WORDS = WS_CNT + NIMG;         // zero range (hist + counts)

typedef float f4 __attribute__((ext_vector_type(4)));
}

__device__ __forceinline__ unsigned key_of(float f) {
  unsigned u = __float_as_uint(f);
  return (u & 0x80000000u) ? ~u : (u | 0x80000000u);  // monotone: bigger float -> bigger key
}

// Find b* = max bucket (of 2048) with suffix-count >= kwant; kr_out = kwant - count(buckets > b*).
// All 256 threads must call. Deterministic -> identical across blocks.
__device__ void scan2048(const unsigned* __restrict__ gh, int kwant,
                         unsigned* sh_cnt, unsigned* sh_sum, int* sh_bk,
                         int& b_out, int& kr_out) {
  const int t = threadIdx.x;
  __syncthreads();
  if (t == 0) { sh_bk[0] = -1; sh_bk[1] = kwant; }
  unsigned local = 0;
  for (int j = 0; j < 8; ++j) { unsigned v = gh[t * 8 + j]; sh_cnt[t * 8 + j] = v; local += v; }
  sh_sum[t] = local;
  __syncthreads();
  unsigned S = 0;
  for (int j = t + 1; j < 256; ++j) S += sh_sum[j];
  int cand_b = -1;
  unsigned cand_above = 0;
  unsigned run = S;
  for (int j = 7; j >= 0; --j) {
    const unsigned cv = sh_cnt[t * 8 + j];
    if (cand_b < 0 && run + cv >= (unsigned)kwant) { cand_b = t * 8 + j; cand_above = run; }
    run += cv;
  }
  if (cand_b >= 0) atomicMax(&sh_bk[0], cand_b);
  __syncthreads();
  if (cand_b >= 0 && cand_b == sh_bk[0]) sh_bk[1] = kwant - (int)cand_above;
  __syncthreads();
  b_out = (sh_bk[0] < 0) ? 0 : sh_bk[0];
  kr_out = sh_bk[1];
}

// Zero the hist/counter words.
__global__ __launch_bounds__(256) void k_zero_ws(unsigned* __restrict__ ws) {
  const int i = blockIdx.x * 256 + threadIdx.x;
  for (int j = i; j < WS_ZERO_WORDS; j += 8 * 256) ws[j] = 0u;
}

// Grid-strided keygen: blocks [0,128) img0, [128,256) img1; keys cached in d_out.
__global__ __launch_bounds__(256) void k_keygen(const float* __restrict__ box_cls,
                                                const float* __restrict__ ctrness,
                                                unsigned* __restrict__ ws,
                                                uint4* __restrict__ keys) {
  __shared__ unsigned hist[2048];
  for (int i = threadIdx.x; i < 2048; i += 256) hist[i] = 0;
  __syncthreads();
  const int n = blockIdx.x >= SEL_BLOCKS;
  const int bi = blockIdx.x - n * SEL_BLOCKS;
  const float* cls = box_cls + n * NCHW;
  const float* ctr = ctrness + n * NHW;
  uint4* mykeys = keys + n * NF4;
  for (int s = 0; s < SEL_ITERS; ++s) {
    const int j4 = s * SEL_STRIDE + bi * 256 + threadIdx.x;
    if (j4 >= NF4) break;
    const int j = j4 * 4;
    const int c = j / NHW;
    const int hw = j - c * NHW;                            // multiple of 4 (NHW%4==0)
    const f4 xv = *reinterpret_cast<const f4*>(cls + j);
    const f4 cv = *reinterpret_cast<const f4*>(ctr + hw);
    unsigned kk[4];
    #pragma unroll
    for (int q = 0; q < 4; ++q) {
      const float sg = 1.0f / (1.0f + expf(-xv[q]));
      float v = -1.0f;
      if (sg > PRE_THRESH) v = sg * (1.0f / (1.0f + expf(-cv[q])));
      const unsigned k = key_of(v);
      kk[q] = k;
      if (k > KEY_ZERO) atomicAdd(&hist[k >> 21], 1u);     // hist positives only
    }
    mykeys[j4] = make_uint4(kk[0], kk[1], kk[2], kk[3]);
  }
  __syncthreads();
  unsigned* gh = ws + WS_HIST1 + n * 2048;
  for (int t = threadIdx.x; t < 2048; t += 256) { unsigned v = hist[t]; if (v) atomicAdd(&gh[t], v); }
}

// Two-phase gather: band members -> LDS buffer (block-local atomics), one global
// reservation per block, coalesced copy-out. Order arbitrary; k_final re-ranks.
__global__ __launch_bounds__(256) void k_gather(const uint4* __restrict__ keys,
                                                unsigned* __restrict__ ws) {
  __shared__ unsigned sh_cnt[2048];
  __shared__ unsigned sh_sum[256];
  __shared__ int sh_bk[2];
  __shared__ unsigned loc[LCAP][2];
  __shared__ int lcnt;
  __shared__ unsigned gbase;
  const int n = blockIdx.x >= SEL_BLOCKS;
  const int bi = blockIdx.x - n * SEL_BLOCKS;
  int b1i, kr;
  scan2048(ws + WS_HIST1 + n * 2048, KTOP, sh_cnt, sh_sum, sh_bk, b1i, kr);
  if (threadIdx.x == 0) lcnt = 0;
  __syncthreads();
  const unsigned b1 = (unsigned)b1i;
  const uint4* mykeys = keys + n * NF4;
  for (int s = 0; s < SEL_ITERS; ++s) {
    const int j4 = s * SEL_STRIDE + bi * 256 + threadIdx.x;
    if (j4 >= NF4) break;
    const uint4 kv = mykeys[j4];
    const unsigned kk[4] = {kv.x, kv.y, kv.z, kv.w};
    #pragma unroll
    for (int q = 0; q < 4; ++q) {
      if ((kk[q] >> 21) < b1) continue;
      const int j = j4 * 4 + q;
      const int c = j / NHW;
      const int hw = j - c * NHW;
      const int p = atomicAdd(&lcnt, 1);
      if (p < LCAP) { loc[p][0] = kk[q]; loc[p][1] = (unsigned)(hw * NC + c); }
    }
  }
  __syncthreads();
  const int lc = min(lcnt, LCAP);
  if (threadIdx.x == 0) gbase = atomicAdd(ws + WS_CNT + n, (unsigned)lc);
  __syncthreads();
  const unsigned gb = gbase;
  for (int i = threadIdx.x; i < lc; i += 256) {
    const unsigned pos = gb + (unsigned)i;
    if (pos < (unsigned)CAP) {
      ws[WS_PAIRS + (n * CAP + (int)pos) * 2]     = loc[i][0];
      ws[WS_PAIRS + (n * CAP + (int)pos) * 2 + 1] = loc[i][1];
    }
  }
}

// One block per image: re-derive b1/krem, refine prefix by two 8-bit levels
// (-> 27-bit threshold), compact members, exact rank WITHIN members (value
// desc, index asc = lax.top_k), build per-slot params.
__global__ __launch_bounds__(256) void k_final(unsigned* __restrict__ ws,
                                               const float* __restrict__ locations,
                                               const float* __restrict__ box_reg,
                                               const float* __restrict__ pemb,
                                               const float* __restrict__ pmar) {
  const int n = blockIdx.x;
  const int t = threadIdx.x;
  __shared__ unsigned sh_cnt[2048];    // scan scratch
  __shared__ unsigned sh_sum[256];
  __shared__ int sh_bk[2];
  __shared__ uint2 P[CAP];             // 32 KiB
  __shared__ unsigned h256[256];
  __shared__ unsigned mKey[MCAP], mRef[MCAP];
  __shared__ int sh_b, sh_t;
  for (int s = t; s < KTOP; s += 256) ws[WS_PARAMS + (n * KTOP + s) * PARAM_WORDS] = 0u;
  int b1i, krem;
  scan2048(ws + WS_HIST1 + n * 2048, KTOP, sh_cnt, sh_sum, sh_bk, b1i, krem);
  const unsigned b1 = (unsigned)b1i;
  const int cnt = min((int)ws[WS_CNT + n], CAP);
  for (int i = t; i < cnt; i += 256) {
    P[i].x = ws[WS_PAIRS + (n * CAP + i) * 2];
    P[i].y = ws[WS_PAIRS + (n * CAP + i) * 2 + 1];
  }
  __syncthreads();

  // ---- two refine levels: prefix 11 -> 19 -> 27 bits ----
  unsigned prefix = b1;
  int shift = 21;
  #pragma unroll
  for (int level = 0; level < 2; ++level) {
    const int newshift = shift - 8;
    h256[t] = 0;
    if (t == 0) sh_b = 0;
    __syncthreads();
    for (int i = t; i < cnt; i += 256) {
      const unsigned k = P[i].x;
      if ((k >> shift) == prefix) atomicAdd(&h256[(k >> newshift) & 255u], 1u);
    }
    __syncthreads();
    const unsigned hv = h256[t];
    unsigned S = 0;                         // suffix-exclusive count for bucket t
    for (int j = t + 1; j < 256; ++j) S += h256[j];
    if (S + hv >= (unsigned)krem) atomicMax(&sh_b, t);
    __syncthreads();
    const int b = sh_b;
    if (t == b) sh_t = krem - (int)S;       // krem within chosen bucket
    __syncthreads();
    krem = sh_t;
    prefix = (prefix << 8) | (unsigned)b;
    shift = newshift;
    __syncthreads();
  }

  // ---- compact members: key >= prefix<<5 (all non-members strictly smaller) ----
  if (t == 0) sh_t = 0;
  __syncthreads();
  for (int i = t; i < cnt; i += 256) {
    const unsigned k = P[i].x;
    if ((k >> 5) >= prefix) {
      const int pos = atomicAdd(&sh_t, 1);
      if (pos < MCAP) { mKey[pos] = k; mRef[pos] = P[i].y; }
    }
  }
  __syncthreads();
  const int m = min(sh_t, MCAP);

  // ---- exact rank within members + emit ----
  for (int i = t; i < m; i += 256) {
    const unsigned ki = mKey[i], ri = mRef[i];
    int rank = 0;
    for (int j = 0; j < m; ++j) {
      const unsigned kj = mKey[j], rj = mRef[j];
      rank += (kj > ki || (kj == ki && rj < ri)) ? 1 : 0;
    }
    if (rank >= KTOP) continue;
    unsigned* pp = ws + WS_PARAMS + (n * KTOP + rank) * PARAM_WORDS;
    int valid = 0;
    if (ki > KEY_ZERO) {
      const int hw = (int)ri / NC;
      const float lx = locations[2 * hw], ly = locations[2 * hw + 1];
      const float rl = box_reg[(n * 4 + 0) * NHW + hw];
      const float rt = box_reg[(n * 4 + 1) * NHW + hw];
      const float rr = box_reg[(n * 4 + 2) * NHW + hw];
      const float rb = box_reg[(n * 4 + 3) * NHW + hw];
      const float x1 = fminf(fmaxf(lx - rl, 0.f), IMG_MAX);
      const float y1 = fminf(fmaxf(ly - rt, 0.f), IMG_MAX);
      const float x2 = fminf(fmaxf(lx + rr, 0.f), IMG_MAX);
      const float y2 = fminf(fmaxf(ly + rb, 0.f), IMG_MAX);
      const int ix0 = max(0, (int)ceilf(x1 * 0.25f));
      const int ix1 = min(OW - 1, (int)floorf(x2 * 0.25f));
      const int iy0 = max(0, (int)ceilf(y1 * 0.25f));
      const int iy1 = min(OH - 1, (int)floorf(y2 * 0.25f));
      if (ix0 <= ix1 && iy0 <= iy1) {
        valid = 1;
        pp[1] = (unsigned)ix0; pp[2] = (unsigned)ix1;
        pp[3] = (unsigned)iy0; pp[4] = (unsigned)iy1;
        reinterpret_cast<float*>(pp)[5] = pmar[n * NHW + hw];
        float* ep = reinterpret_cast<float*>(pp) + 8;
        #pragma unroll
        for (int d = 0; d < NDIM; ++d) ep[d] = pemb[(n * NDIM + d) * NHW + hw];
      }
    }
    pp[0] = (unsigned)valid;
  }
}

// Fused output kernel, disjoint write ownership:
//  blocks [0, NZB): zero tiles (nk = b/6, 64 rows each), skipping exactly the
//    padded-box f4 range of their nk.
//  blocks [NZB, NZB+400): box compute over the padded f4-aligned region,
//    writing exp(-d2*margin) inside the box and 0.0 on the f4 padding.
__global__ __launch_bounds__(256) void k_out(const float* __restrict__ pix,
                                             const unsigned* __restrict__ ws,
                                             float* __restrict__ out) {
  const int bid = blockIdx.x;
  const int t = threadIdx.x;
  if (bid < NZB) {
    const int nk = bid / ZTILES;
    const int rt = bid - nk * ZTILES;
    const int y0 = rt * 64;
    const unsigned* meta = ws + WS_PARAMS + nk * PARAM_WORDS;
    f4* ob4 = reinterpret_cast<f4*>(out + (size_t)nk * (OH * OW)) + y0 * (OW / 4);
    const f4 z = {0.f, 0.f, 0.f, 0.f};
    int qa = 0, qb = -1, iy0 = 0, iy1 = -1;
    bool overlap = false;
    if (meta[0]) {
      iy0 = (int)meta[3]; iy1 = (int)meta[4];
      if (iy1 >= y0 && iy0 < y0 + 64) {
        overlap = true;
        qa = (int)meta[1] >> 2;
        qb = (int)meta[2] >> 2;
      }
    }
    if (!overlap) {                      // fast path: 24 contiguous f4 stores/thread
      #pragma unroll
      for (int i = 0; i < 24; ++i) ob4[i * 256 + t] = z;
    } else {
      for (int i = 0; i < 24; ++i) {
        const int idx = i * 256 + t;
        const int y = y0 + idx / 96;
        const int q = idx - (idx / 96) * 96;
        if (y >= iy0 && y <= iy1 && q >= qa && q <= qb) continue;  // box block owns
        ob4[idx] = z;
      }
    }
    return;
  }

  // ---- box compute path ----
  const int nk = bid - NZB;
  const unsigned* meta = ws + WS_PARAMS + nk * PARAM_WORDS;
  if (meta[0] == 0u) return;
  const int ix0 = (int)meta[1], ix1 = (int)meta[2];
  const int iy0 = (int)meta[3], iy1 = (int)meta[4];
  const int xp0 = (ix0 >> 2) << 2;         // padded f4-aligned column range
  const int xp1 = (ix1 >> 2) * 4 + 3;
  const float margin = __uint_as_float(meta[5]);
  float e[NDIM];
  {
    const float4* e4 = reinterpret_cast<const float4*>(meta + 8);
    #pragma unroll
    for (int q = 0; q < NDIM / 4; ++q) {
      const float4 v = e4[q];
      e[4 * q + 0] = v.x; e[4 * q + 1] = v.y; e[4 * q + 2] = v.z; e[4 * q + 3] = v.w;
    }
  }
  const int n = nk / KTOP;
  const float* peb = pix + (size_t)n * NDIM * PH * PW;
  float* ob = out + (size_t)nk * (OH * OW);

  const int tx = t & 63;             // column lane
  const int ts = t >> 6;             // row strip 0..3
  const int h = iy1 - iy0 + 1;
  const int shh = (h + 3) >> 2;
  const int ybeg = iy0 + ts * shh;
  const int yend = min(iy0 + (ts + 1) * shh, iy1 + 1);

  for (int c = xp0 + tx; c <= xp1; c += 64) {
    const bool inx = (c >= ix0) && (c <= ix1);
    const float sx = 0.5f * (float)c - 0.25f;
    const float xf = floorf(sx);
    const float fx = sx - xf;
    const int xs0 = max((int)xf, 0);
    const int xs1 = min((int)xf + 1, PW - 1);
    float qa_[NDIM], qb_[NDIM];
    int ra = -9, rb = -9;
    for (int y = ybeg; y < yend; ++y) {
      float val = 0.f;
      if (inx) {
        const float sy = 0.5f * (float)y - 0.25f;
        const float yf = floorf(sy);
        const float fy = sy - yf;
        const int ys0 = max((int)yf, 0);
        const int ys1 = min((int)yf + 1, PH - 1);
        if (ys0 != ra) {
          if (ys0 == rb) {
            #pragma unroll
            for (int d = 0; d < NDIM; ++d) qa_[d] = qb_[d];
          } else {
            const float* p = peb + (size_t)ys0 * PW;
            #pragma unroll
            for (int d = 0; d < NDIM; ++d)
              qa_[d] = (1.f - fx) * p[d * PH * PW + xs0] + fx * p[d * PH * PW + xs1];
          }
          ra = ys0;
        }
        if (ys1 != rb) {
          if (ys1 == ra) {
            #pragma unroll
            for (int d = 0; d < NDIM; ++d) qb_[d] = qa_[d];
          } else {
            const float* p = peb + (size_t)ys1 * PW;
            #pragma unroll
            for (int d = 0; d < NDIM; ++d)
              qb_[d] = (1.f - fx) * p[d * PH * PW + xs0] + fx * p[d * PH * PW + xs1];
          }
          rb = ys1;
        }
        float d2 = 0.f;
        #pragma unroll
        for (int d = 0; d < NDIM; ++d) {
          const float pv = qa_[d] + fy * (qb_[d] - qa_[d]);
          const float df = e[d] - pv;
          d2 = fmaf(df, df, d2);
        }
        val = expf(-d2 * margin);
      }
      ob[(size_t)y * OW + c] = val;
    }
  }
}

extern "C" void kernel_launch(void* const* d_in, const int* in_sizes, int n_in,
                              void* d_out, int out_size, void* d_ws, size_t ws_size,
                              hipStream_t stream) {
  const float* locations = (const float*)d_in[0];
  const float* box_cls   = (const float*)d_in[1];
  const float* box_reg   = (const float*)d_in[2];
  const float* ctrness   = (const float*)d_in[3];
  const float* pemb      = (const float*)d_in[4];
  const float* pmar      = (const float*)d_in[5];
  const float* pix       = (const float*)d_in[6];
  float* out = (float*)d_out;
  unsigned* ws = (unsigned*)d_ws;
  uint4* keys = (uint4*)d_out;  // 5.9 MB scratch; fully overwritten by k_out

  k_zero_ws<<<dim3(8), dim3(256), 0, stream>>>(ws);
  k_keygen <<<dim3(2 * SEL_BLOCKS), dim3(256), 0, stream>>>(box_cls, ctrness, ws, keys);
  k_gather <<<dim3(2 * SEL_BLOCKS), dim3(256), 0, stream>>>(keys, ws);
  k_final  <<<dim3(NIMG), dim3(256), 0, stream>>>(ws, locations, box_reg, pemb, pmar);
  k_out    <<<dim3(NZB + NIMG * KTOP), dim3(256), 0, stream>>>(pix, ws, out);
}

// Round 8
// 100.608 us; speedup vs baseline: 2.9188x; 1.0731x over previous
//
#include <hip/hip_runtime.h>
#include <cmath>

// EmbedMaskPostProcessor: top-k select + box decode + embedding-distance masks.
// Output [2,200,384,384] f32 = 236 MB, <1% nonzero -> write-BW bound (~35us floor).
// R8: single fused selection kernel (keys in registers, manual spin barrier among
// 256 co-resident blocks, per-image last-block final). Cross-block pair traffic
// via __hip_atomic AGENT ops (per-XCD L2 non-coherent for plain stores).
// k_out: box-compute blocks first so their latency overlaps the zero stream.

namespace {
constexpr int NIMG = 2;
constexpr int NC   = 80;
constexpr int NHW  = 96 * 96;        // 9216
constexpr int NCHW = NC * NHW;       // 737280
constexpr int NDIM = 32;
constexpr int PH = 192, PW = 192;    // pixel_embed spatial
constexpr int OH = 384, OW = 384;    // output mask spatial
constexpr int KTOP = 200;
constexpr int CAP = 4096;            // gathered band candidates per image
constexpr int MCAP = 1024;           // member cap after 27-bit refine
constexpr int LCAP = 512;            // per-block gather buffer
constexpr float PRE_THRESH = 0.05f;
constexpr unsigned KEY_ZERO = 0x80000000u;  // key of +0.0f; key > this <=> value > 0
constexpr float IMG_MAX = 767.0f;

constexpr int NBOX = NIMG * KTOP;    // 400 box-compute blocks
constexpr int ZTILES = 6;            // 64-row zero tiles per (n,k)
constexpr int NZB = NBOX * ZTILES;   // 2400 zero blocks

constexpr int NF4 = NCHW / 4;        // 184320 float4 per image
constexpr int SEL_BLOCKS = 128;      // selection blocks per image (grid = 256)
constexpr int SEL_STRIDE = SEL_BLOCKS * 256;                    // 32768
constexpr int SEL_ITERS = (NF4 + SEL_STRIDE - 1) / SEL_STRIDE;  // 6

// ws layout (4-byte words)
constexpr int WS_HIST1  = 0;                         // [NIMG][2048]
constexpr int WS_CNT    = WS_HIST1 + NIMG * 2048;    // [NIMG]
constexpr int WS_BAR    = WS_CNT + NIMG;             // [1] spin barrier
constexpr int WS_TICK   = WS_BAR + 1;                // [NIMG] last-block tickets
constexpr int WS_ZERO_WORDS = WS_TICK + NIMG;        // 4101
constexpr int WS_PAIRS  = 4104;                      // [NIMG][CAP][2] {key,ref}
constexpr int WS_PARAMS = WS_PAIRS + NIMG * CAP * 2; // [NIMG][KTOP][40]
constexpr int PARAM_WORDS = 40;  // [0]=valid [1..4]=ix0,ix1,iy0,iy1 [5]=margin [8..39]=e

typedef float f4 __attribute__((ext_vector_type(4)));
}

__device__ __forceinline__ unsigned key_of(float f) {
  unsigned u = __float_as_uint(f);
  return (u & 0x80000000u) ? ~u : (u | 0x80000000u);  // monotone: bigger float -> bigger key
}

// Zero hist/counters/barrier words (must not rely on cross-call state).
__global__ __launch_bounds__(256) void k_zero_ws(unsigned* __restrict__ ws) {
  for (int j = threadIdx.x; j < WS_ZERO_WORDS; j += 256) ws[j] = 0u;
}

// Fused selection: keygen (keys in regs) -> hist -> spin barrier -> scan ->
// gather (LDS two-phase) -> per-image last-block exact-rank final.
__global__ __launch_bounds__(256) void k_select(
    const float* __restrict__ box_cls, const float* __restrict__ ctrness,
    const float* __restrict__ locations, const float* __restrict__ box_reg,
    const float* __restrict__ pemb, const float* __restrict__ pmar,
    unsigned* __restrict__ ws) {
  __shared__ unsigned hist[2048];          // phase1 hist; phase2 scan scratch
  __shared__ unsigned sh_sum[256];
  __shared__ int sh_bk[2];
  __shared__ unsigned loc[LCAP][2];
  __shared__ int lcnt;
  __shared__ unsigned gbase;
  __shared__ int sh_last;
  const int t = threadIdx.x;
  const int n = blockIdx.x >= SEL_BLOCKS;
  const int bi = blockIdx.x - n * SEL_BLOCKS;

  // ---- phase 1: keygen into registers + LDS hist (positives only) ----
  for (int i = t; i < 2048; i += 256) hist[i] = 0;
  __syncthreads();
  const float* cls = box_cls + n * NCHW;
  const float* ctr = ctrness + n * NHW;
  unsigned kk[SEL_ITERS][4];
  #pragma unroll
  for (int s = 0; s < SEL_ITERS; ++s) {
    const int j4 = s * SEL_STRIDE + bi * 256 + t;
    if (j4 < NF4) {
      const int j = j4 * 4;
      const int c = j / NHW;
      const int hw = j - c * NHW;                          // multiple of 4
      const f4 xv = *reinterpret_cast<const f4*>(cls + j);
      const f4 cv = *reinterpret_cast<const f4*>(ctr + hw);
      #pragma unroll
      for (int q = 0; q < 4; ++q) {
        const float sg = 1.0f / (1.0f + expf(-xv[q]));
        float v = -1.0f;
        if (sg > PRE_THRESH) v = sg * (1.0f / (1.0f + expf(-cv[q])));
        const unsigned k = key_of(v);
        kk[s][q] = k;
        if (k > KEY_ZERO) atomicAdd(&hist[k >> 21], 1u);
      }
    } else {
      #pragma unroll
      for (int q = 0; q < 4; ++q) kk[s][q] = 0u;
    }
  }
  __syncthreads();
  {
    unsigned* gh = ws + WS_HIST1 + n * 2048;
    for (int i = t; i < 2048; i += 256) { unsigned v = hist[i]; if (v) atomicAdd(&gh[i], v); }
  }

  // ---- spin barrier across all 256 blocks (capacity >= grid -> co-resident) ----
  __syncthreads();                       // compiler drains vmcnt before s_barrier
  if (t == 0) {
    atomicAdd(ws + WS_BAR, 1u);
    while (__hip_atomic_load(ws + WS_BAR, __ATOMIC_RELAXED,
                             __HIP_MEMORY_SCOPE_AGENT) < (unsigned)(2 * SEL_BLOCKS)) {
      __builtin_amdgcn_s_sleep(2);
    }
  }
  __syncthreads();

  // ---- phase 2: scan global hist for b1/krem (plain loads: hist truth is at
  //      the device coherence point, no per-XCD dirty copies exist) ----
  if (t == 0) { sh_bk[0] = -1; sh_bk[1] = KTOP; }
  {
    const unsigned* gh = ws + WS_HIST1 + n * 2048;
    unsigned local = 0;
    for (int j = 0; j < 8; ++j) { unsigned v = gh[t * 8 + j]; hist[t * 8 + j] = v; local += v; }
    sh_sum[t] = local;
  }
  __syncthreads();
  {
    unsigned S = 0;
    for (int j = t + 1; j < 256; ++j) S += sh_sum[j];
    int cand_b = -1;
    unsigned cand_above = 0;
    unsigned run = S;
    for (int j = 7; j >= 0; --j) {
      const unsigned cv = hist[t * 8 + j];
      if (cand_b < 0 && run + cv >= (unsigned)KTOP) { cand_b = t * 8 + j; cand_above = run; }
      run += cv;
    }
    if (cand_b >= 0) atomicMax(&sh_bk[0], cand_b);
    __syncthreads();
    if (cand_b >= 0 && cand_b == sh_bk[0]) sh_bk[1] = KTOP - (int)cand_above;
    __syncthreads();
  }
  const unsigned b1 = (unsigned)(sh_bk[0] < 0 ? 0 : sh_bk[0]);
  int krem = sh_bk[1];

  // ---- gather band members from registers -> LDS -> one global reservation ----
  if (t == 0) lcnt = 0;
  __syncthreads();
  #pragma unroll
  for (int s = 0; s < SEL_ITERS; ++s) {
    #pragma unroll
    for (int q = 0; q < 4; ++q) {
      const unsigned k = kk[s][q];
      if ((k >> 21) < b1) continue;
      const int j = (s * SEL_STRIDE + bi * 256 + t) * 4 + q;
      const int c = j / NHW;
      const int hw = j - c * NHW;
      const int p = atomicAdd(&lcnt, 1);
      if (p < LCAP) { loc[p][0] = k; loc[p][1] = (unsigned)(hw * NC + c); }
    }
  }
  __syncthreads();
  const int lc = min(lcnt, LCAP);
  if (t == 0) gbase = atomicAdd(ws + WS_CNT + n, (unsigned)lc);
  __syncthreads();
  for (int i = t; i < lc; i += 256) {
    const unsigned pos = gbase + (unsigned)i;
    if (pos < (unsigned)CAP) {   // AGENT stores: plain stores are not cross-XCD coherent
      __hip_atomic_store(&ws[WS_PAIRS + (n * CAP + (int)pos) * 2], loc[i][0],
                         __ATOMIC_RELAXED, __HIP_MEMORY_SCOPE_AGENT);
      __hip_atomic_store(&ws[WS_PAIRS + (n * CAP + (int)pos) * 2 + 1], loc[i][1],
                         __ATOMIC_RELAXED, __HIP_MEMORY_SCOPE_AGENT);
    }
  }

  // ---- per-image last-block ticket ----
  __syncthreads();                       // drain pair stores before ticket
  if (t == 0) {
    const unsigned old = atomicAdd(ws + WS_TICK + n, 1u);
    sh_last = (old == (unsigned)(SEL_BLOCKS - 1)) ? 1 : 0;
  }
  __syncthreads();
  if (!sh_last) return;

  // ---- phase 3 (one block per image): refine to 27-bit prefix, compact
  //      members, exact rank (value desc, index asc = lax.top_k), emit params ----
  __shared__ uint2 P[CAP];               // 32 KiB
  __shared__ unsigned h256[256];
  __shared__ unsigned mKey[MCAP], mRef[MCAP];
  __shared__ int sh_b, sh_t;
  for (int s = t; s < KTOP; s += 256) ws[WS_PARAMS + (n * KTOP + s) * PARAM_WORDS] = 0u;
  const int cnt = min((int)__hip_atomic_load(ws + WS_CNT + n, __ATOMIC_RELAXED,
                                             __HIP_MEMORY_SCOPE_AGENT), CAP);
  for (int i = t; i < cnt; i += 256) {
    P[i].x = __hip_atomic_load(&ws[WS_PAIRS + (n * CAP + i) * 2],
                               __ATOMIC_RELAXED, __HIP_MEMORY_SCOPE_AGENT);
    P[i].y = __hip_atomic_load(&ws[WS_PAIRS + (n * CAP + i) * 2 + 1],
                               __ATOMIC_RELAXED, __HIP_MEMORY_SCOPE_AGENT);
  }
  __syncthreads();

  unsigned prefix = b1;
  int shift = 21;
  #pragma unroll
  for (int level = 0; level < 2; ++level) {
    const int newshift = shift - 8;
    h256[t] = 0;
    if (t == 0) sh_b = 0;
    __syncthreads();
    for (int i = t; i < cnt; i += 256) {
      const unsigned k = P[i].x;
      if ((k >> shift) == prefix) atomicAdd(&h256[(k >> newshift) & 255u], 1u);
    }
    __syncthreads();
    const unsigned hv = h256[t];
    unsigned S = 0;
    for (int j = t + 1; j < 256; ++j) S += h256[j];
    if (S + hv >= (unsigned)krem) atomicMax(&sh_b, t);
    __syncthreads();
    const int b = sh_b;
    if (t == b) sh_t = krem - (int)S;
    __syncthreads();
    krem = sh_t;
    prefix = (prefix << 8) | (unsigned)b;
    shift = newshift;
    __syncthreads();
  }

  if (t == 0) sh_t = 0;
  __syncthreads();
  for (int i = t; i < cnt; i += 256) {
    const unsigned k = P[i].x;
    if ((k >> 5) >= prefix) {
      const int pos = atomicAdd(&sh_t, 1);
      if (pos < MCAP) { mKey[pos] = k; mRef[pos] = P[i].y; }
    }
  }
  __syncthreads();
  const int m = min(sh_t, MCAP);

  for (int i = t; i < m; i += 256) {
    const unsigned ki = mKey[i], ri = mRef[i];
    int rank = 0;
    for (int j = 0; j < m; ++j) {
      const unsigned kj = mKey[j], rj = mRef[j];
      rank += (kj > ki || (kj == ki && rj < ri)) ? 1 : 0;
    }
    if (rank >= KTOP) continue;
    unsigned* pp = ws + WS_PARAMS + (n * KTOP + rank) * PARAM_WORDS;
    int valid = 0;
    if (ki > KEY_ZERO) {
      const int hw = (int)ri / NC;
      const float lx = locations[2 * hw], ly = locations[2 * hw + 1];
      const float rl = box_reg[(n * 4 + 0) * NHW + hw];
      const float rt = box_reg[(n * 4 + 1) * NHW + hw];
      const float rr = box_reg[(n * 4 + 2) * NHW + hw];
      const float rb = box_reg[(n * 4 + 3) * NHW + hw];
      const float x1 = fminf(fmaxf(lx - rl, 0.f), IMG_MAX);
      const float y1 = fminf(fmaxf(ly - rt, 0.f), IMG_MAX);
      const float x2 = fminf(fmaxf(lx + rr, 0.f), IMG_MAX);
      const float y2 = fminf(fmaxf(ly + rb, 0.f), IMG_MAX);
      const int ix0 = max(0, (int)ceilf(x1 * 0.25f));
      const int ix1 = min(OW - 1, (int)floorf(x2 * 0.25f));
      const int iy0 = max(0, (int)ceilf(y1 * 0.25f));
      const int iy1 = min(OH - 1, (int)floorf(y2 * 0.25f));
      if (ix0 <= ix1 && iy0 <= iy1) {
        valid = 1;
        pp[1] = (unsigned)ix0; pp[2] = (unsigned)ix1;
        pp[3] = (unsigned)iy0; pp[4] = (unsigned)iy1;
        reinterpret_cast<float*>(pp)[5] = pmar[n * NHW + hw];
        float* ep = reinterpret_cast<float*>(pp) + 8;
        #pragma unroll
        for (int d = 0; d < NDIM; ++d) ep[d] = pemb[(n * NDIM + d) * NHW + hw];
      }
    }
    pp[0] = (unsigned)valid;
  }
}

// Fused output kernel, disjoint write ownership. Box blocks FIRST (latency-bound
// gathered reads overlap the zero write stream instead of trailing it).
__global__ __launch_bounds__(256) void k_out(const float* __restrict__ pix,
                                             const unsigned* __restrict__ ws,
                                             float* __restrict__ out) {
  const int bid = blockIdx.x;
  const int t = threadIdx.x;
  if (bid >= NBOX) {
    // ---- zero path ----
    const int zb = bid - NBOX;
    const int nk = zb / ZTILES;
    const int rt = zb - nk * ZTILES;
    const int y0 = rt * 64;
    const unsigned* meta = ws + WS_PARAMS + nk * PARAM_WORDS;
    f4* ob4 = reinterpret_cast<f4*>(out + (size_t)nk * (OH * OW)) + y0 * (OW / 4);
    const f4 z = {0.f, 0.f, 0.f, 0.f};
    int qa = 0, qb = -1, iy0 = 0, iy1 = -1;
    bool overlap = false;
    if (meta[0]) {
      iy0 = (int)meta[3]; iy1 = (int)meta[4];
      if (iy1 >= y0 && iy0 < y0 + 64) {
        overlap = true;
        qa = (int)meta[1] >> 2;
        qb = (int)meta[2] >> 2;
      }
    }
    if (!overlap) {                      // fast path: 24 contiguous f4 stores/thread
      #pragma unroll
      for (int i = 0; i < 24; ++i) ob4[i * 256 + t] = z;
    } else {
      for (int i = 0; i < 24; ++i) {
        const int idx = i * 256 + t;
        const int y = y0 + idx / 96;
        const int q = idx - (idx / 96) * 96;
        if (y >= iy0 && y <= iy1 && q >= qa && q <= qb) continue;  // box block owns
        ob4[idx] = z;
      }
    }
    return;
  }

  // ---- box compute path ----
  const int nk = bid;
  const unsigned* meta = ws + WS_PARAMS + nk * PARAM_WORDS;
  if (meta[0] == 0u) return;
  const int ix0 = (int)meta[1], ix1 = (int)meta[2];
  const int iy0 = (int)meta[3], iy1 = (int)meta[4];
  const int xp0 = (ix0 >> 2) << 2;         // padded f4-aligned column range
  const int xp1 = (ix1 >> 2) * 4 + 3;
  const float margin = __uint_as_float(meta[5]);
  float e[NDIM];
  {
    const float4* e4 = reinterpret_cast<const float4*>(meta + 8);
    #pragma unroll
    for (int q = 0; q < NDIM / 4; ++q) {
      const float4 v = e4[q];
      e[4 * q + 0] = v.x; e[4 * q + 1] = v.y; e[4 * q + 2] = v.z; e[4 * q + 3] = v.w;
    }
  }
  const int n = nk / KTOP;
  const float* peb = pix + (size_t)n * NDIM * PH * PW;
  float* ob = out + (size_t)nk * (OH * OW);

  const int tx = t & 63;             // column lane
  const int ts = t >> 6;             // row strip 0..3
  const int h = iy1 - iy0 + 1;
  const int shh = (h + 3) >> 2;
  const int ybeg = iy0 + ts * shh;
  const int yend = min(iy0 + (ts + 1) * shh, iy1 + 1);

  for (int c = xp0 + tx; c <= xp1; c += 64) {
    const bool inx = (c >= ix0) && (c <= ix1);
    const float sx = 0.5f * (float)c - 0.25f;
    const float xf = floorf(sx);
    const float fx = sx - xf;
    const int xs0 = max((int)xf, 0);
    const int xs1 = min((int)xf + 1, PW - 1);
    float qa_[NDIM], qb_[NDIM];
    int ra = -9, rb = -9;
    for (int y = ybeg; y < yend; ++y) {
      float val = 0.f;
      if (inx) {
        const float sy = 0.5f * (float)y - 0.25f;
        const float yf = floorf(sy);
        const float fy = sy - yf;
        const int ys0 = max((int)yf, 0);
        const int ys1 = min((int)yf + 1, PH - 1);
        if (ys0 != ra) {
          if (ys0 == rb) {
            #pragma unroll
            for (int d = 0; d < NDIM; ++d) qa_[d] = qb_[d];
          } else {
            const float* p = peb + (size_t)ys0 * PW;
            #pragma unroll
            for (int d = 0; d < NDIM; ++d)
              qa_[d] = (1.f - fx) * p[d * PH * PW + xs0] + fx * p[d * PH * PW + xs1];
          }
          ra = ys0;
        }
        if (ys1 != rb) {
          if (ys1 == ra) {
            #pragma unroll
            for (int d = 0; d < NDIM; ++d) qb_[d] = qa_[d];
          } else {
            const float* p = peb + (size_t)ys1 * PW;
            #pragma unroll
            for (int d = 0; d < NDIM; ++d)
              qb_[d] = (1.f - fx) * p[d * PH * PW + xs0] + fx * p[d * PH * PW + xs1];
          }
          rb = ys1;
        }
        float d2 = 0.f;
        #pragma unroll
        for (int d = 0; d < NDIM; ++d) {
          const float pv = qa_[d] + fy * (qb_[d] - qa_[d]);
          const float df = e[d] - pv;
          d2 = fmaf(df, df, d2);
        }
        val = expf(-d2 * margin);
      }
      ob[(size_t)y * OW + c] = val;
    }
  }
}

extern "C" void kernel_launch(void* const* d_in, const int* in_sizes, int n_in,
                              void* d_out, int out_size, void* d_ws, size_t ws_size,
                              hipStream_t stream) {
  const float* locations = (const float*)d_in[0];
  const float* box_cls   = (const float*)d_in[1];
  const float* box_reg   = (const float*)d_in[2];
  const float* ctrness   = (const float*)d_in[3];
  const float* pemb      = (const float*)d_in[4];
  const float* pmar      = (const float*)d_in[5];
  const float* pix       = (const float*)d_in[6];
  float* out = (float*)d_out;
  unsigned* ws = (unsigned*)d_ws;

  k_zero_ws<<<dim3(1), dim3(256), 0, stream>>>(ws);
  k_select <<<dim3(2 * SEL_BLOCKS), dim3(256), 0, stream>>>(
      box_cls, ctrness, locations, box_reg, pemb, pmar, ws);
  k_out    <<<dim3(NBOX + NZB), dim3(256), 0, stream>>>(pix, ws, out);
}